// Round 5
// baseline (441.743 us; speedup 1.0000x reference)
//
#include <hip/hip_runtime.h>

#define LDS_XPAD 68
#define MAXBUK 256
#define BF_CHUNK 2048

typedef unsigned short ushort_t;
typedef unsigned int uint_t;

__device__ __forceinline__ ushort_t f2bf(float x) {
    uint_t u = __float_as_uint(x);
    uint_t r = (u + 0x7FFFu + ((u >> 16) & 1u)) >> 16;
    return (ushort_t)r;
}
__device__ __forceinline__ float bf2f(ushort_t h) {
    return __uint_as_float((uint_t)h << 16);
}

__global__ void zero_int_kernel(int* p, int n) {
    int i = blockIdx.x * blockDim.x + threadIdx.x;
    if (i < n) p[i] = 0;
}

// Combined bucket histogram + per-node degree for BOTH relations in one pass.
// Edge index e < Ea -> relation a, else relation b. deg2/bcnt2 are concatenated.
__global__ void bhist2_kernel(const int* __restrict__ dsta, const int* __restrict__ dstb,
                              int* __restrict__ bcnt2, int* __restrict__ deg2,
                              int Ea, int Et, int shift, int nbuk, int n) {
    __shared__ int h[MAXBUK];
    for (int i = threadIdx.x; i < 2 * nbuk; i += blockDim.x) h[i] = 0;
    __syncthreads();
    int stride = gridDim.x * blockDim.x;
    for (int e = blockIdx.x * blockDim.x + threadIdx.x; e < Et; e += stride) {
        int rel = (e >= Ea);
        int d = rel ? dstb[e - Ea] : dsta[e];
        atomicAdd(&h[(rel ? nbuk : 0) + (d >> shift)], 1);
        atomicAdd(&deg2[(rel ? n : 0) + d], 1);
    }
    __syncthreads();
    for (int i = threadIdx.x; i < 2 * nbuk; i += blockDim.x)
        if (h[i]) atomicAdd(&bcnt2[i], h[i]);
}

__global__ void bscan_kernel(const int* __restrict__ bcnt, int* __restrict__ bcursor, int nbuk2) {
    __shared__ int s[256];
    int t = threadIdx.x;
    int v = (t < nbuk2) ? bcnt[t] : 0;
    s[t] = v;
    __syncthreads();
    #pragma unroll
    for (int d = 1; d < 256; d <<= 1) {
        int u = (t >= d) ? s[t - d] : 0;
        __syncthreads();
        s[t] += u;
        __syncthreads();
    }
    if (t < nbuk2) bcursor[t] = s[t] - v;   // exclusive
}

// Bin (src, dst2) pairs by combined bucket id, chunk-local LDS counting.
__global__ void bfill2_kernel(const int* __restrict__ eia, const int* __restrict__ eib,
                              int* __restrict__ bcursor, int2* __restrict__ pairs,
                              int Ea, int Eb, int Et, int shift, int nbuk, int n) {
    __shared__ int cnt[MAXBUK];
    __shared__ int base[MAXBUK];
    __shared__ int off[MAXBUK];
    const int t = threadIdx.x;
    const long long e0 = (long long)blockIdx.x * BF_CHUNK;
    const int nedge = (int)min((long long)BF_CHUNK, (long long)Et - e0);
    const int nbuk2 = 2 * nbuk;
    for (int i = t; i < nbuk2; i += 256) cnt[i] = 0;
    __syncthreads();
    for (int i = t; i < nedge; i += 256) {
        long long e = e0 + i;
        int rel = (e >= Ea);
        int d = rel ? eib[Eb + (e - Ea)] : eia[Ea + e];
        atomicAdd(&cnt[(rel ? nbuk : 0) + (d >> shift)], 1);
    }
    __syncthreads();
    for (int i = t; i < nbuk2; i += 256) {
        off[i] = 0;
        base[i] = cnt[i] ? atomicAdd(&bcursor[i], cnt[i]) : 0;
    }
    __syncthreads();
    for (int i = t; i < nedge; i += 256) {
        long long e = e0 + i;
        int rel = (e >= Ea);
        int s, d;
        if (rel) { s = eib[e - Ea]; d = eib[Eb + (e - Ea)]; }
        else     { s = eia[e];      d = eia[Ea + e]; }
        int b = (rel ? nbuk : 0) + (d >> shift);
        int p = base[b] + atomicAdd(&off[b], 1);
        pairs[p] = make_int2(s, (rel ? n : 0) + d);
    }
}

__global__ void lfill_kernel(const int2* __restrict__ pairs, int* __restrict__ cursor2,
                             int* __restrict__ col2, int Et) {
    int e = blockIdx.x * blockDim.x + threadIdx.x;
    if (e < Et) {
        int2 p = pairs[e];
        int pos = atomicAdd(&cursor2[p.y], 1);
        col2[pos] = p.x;
    }
}

__global__ void scan1_kernel(const int* __restrict__ deg, int* __restrict__ rowptr,
                             int* __restrict__ partials, int n2) {
    __shared__ int s[256];
    int i = blockIdx.x * 256 + threadIdx.x;
    int v = (i < n2) ? deg[i] : 0;
    s[threadIdx.x] = v;
    __syncthreads();
    #pragma unroll
    for (int d = 1; d < 256; d <<= 1) {
        int t = (threadIdx.x >= d) ? s[threadIdx.x - d] : 0;
        __syncthreads();
        s[threadIdx.x] += t;
        __syncthreads();
    }
    if (i < n2) rowptr[i] = s[threadIdx.x] - v;
    if (threadIdx.x == 255) partials[blockIdx.x] = s[255];
}

__global__ void scan2_kernel(int* partials, int nb) {
    int lane = threadIdx.x;
    int acc = 0;
    for (int base = 0; base < nb; base += 64) {
        int i = base + lane;
        int v = (i < nb) ? partials[i] : 0;
        int s = v;
        #pragma unroll
        for (int d = 1; d < 64; d <<= 1) {
            int t = __shfl_up(s, d);
            if (lane >= d) s += t;
        }
        if (i < nb) partials[i] = acc + s - v;
        acc += __shfl(s, 63);
    }
}

__global__ void scan3_kernel(int* __restrict__ rowptr, const int* __restrict__ partials,
                             int* __restrict__ cursor, const int* __restrict__ deg,
                             float* __restrict__ dinv, int n2, int Et) {
    int i = blockIdx.x * 256 + threadIdx.x;
    if (i < n2) {
        int v = rowptr[i] + partials[blockIdx.x];
        rowptr[i] = v;
        cursor[i] = v;
        dinv[i] = rsqrtf((float)(deg[i] + 1));
    }
    if (i == 0) rowptr[n2] = Et;
}

// ---- dual-weight GEMM (layer 1, M=64): ya/yb written as bf16 ----
__global__ void gemm2_scale_bf16_kernel(const float* __restrict__ X,
                                        const float* __restrict__ Wa, const float* __restrict__ Wb,
                                        const float* __restrict__ dinva, const float* __restrict__ dinvb,
                                        ushort_t* __restrict__ ya, ushort_t* __restrict__ yb, int n) {
    constexpr int M = 64;
    __shared__ float xs[64 * LDS_XPAD];
    __shared__ float wsa[64 * M];
    __shared__ float wsb[64 * M];
    const int tid = threadIdx.x;
    const int row = tid >> 2;
    const int cg  = tid & 3;
    const int grow = blockIdx.x * 64 + row;

    {
        float4 v0, v1, v2, v3;
        if (grow < n) {
            const float4* xr = reinterpret_cast<const float4*>(X + (size_t)grow * 64 + cg * 16);
            v0 = xr[0]; v1 = xr[1]; v2 = xr[2]; v3 = xr[3];
        } else {
            v0 = v1 = v2 = v3 = make_float4(0.f, 0.f, 0.f, 0.f);
        }
        float4* xd = reinterpret_cast<float4*>(&xs[row * LDS_XPAD + cg * 16]);
        xd[0] = v0; xd[1] = v1; xd[2] = v2; xd[3] = v3;
    }
    {
        const float4* sa = reinterpret_cast<const float4*>(Wa);
        const float4* sb = reinterpret_cast<const float4*>(Wb);
        float4* da = reinterpret_cast<float4*>(wsa);
        float4* db = reinterpret_cast<float4*>(wsb);
        #pragma unroll
        for (int i = 0; i < 4; ++i) {
            int idx = tid + i * 256;
            da[idx] = sa[idx]; db[idx] = sb[idx];
        }
    }
    __syncthreads();

    constexpr int CPT = 16;
    float acca[CPT], accb[CPT];
    #pragma unroll
    for (int j = 0; j < CPT; ++j) { acca[j] = 0.0f; accb[j] = 0.0f; }

    for (int k = 0; k < 64; ++k) {
        float xk = xs[row * LDS_XPAD + k];
        #pragma unroll
        for (int j = 0; j < CPT; ++j) {
            acca[j] += xk * wsa[k * M + cg * CPT + j];
            accb[j] += xk * wsb[k * M + cg * CPT + j];
        }
    }

    if (grow < n) {
        float sa = dinva[grow], sb = dinvb[grow];
        uint_t pka[8], pkb[8];
        #pragma unroll
        for (int j = 0; j < 8; ++j) {
            pka[j] = (uint_t)f2bf(acca[2 * j] * sa) | ((uint_t)f2bf(acca[2 * j + 1] * sa) << 16);
            pkb[j] = (uint_t)f2bf(accb[2 * j] * sb) | ((uint_t)f2bf(accb[2 * j + 1] * sb) << 16);
        }
        uint4* pa = reinterpret_cast<uint4*>(ya + (size_t)grow * 64 + cg * 16);
        uint4* pb = reinterpret_cast<uint4*>(yb + (size_t)grow * 64 + cg * 16);
        pa[0] = make_uint4(pka[0], pka[1], pka[2], pka[3]);
        pa[1] = make_uint4(pka[4], pka[5], pka[6], pka[7]);
        pb[0] = make_uint4(pkb[0], pkb[1], pkb[2], pkb[3]);
        pb[1] = make_uint4(pkb[4], pkb[5], pkb[6], pkb[7]);
    }
}

// ---- dual-weight GEMM (layer 2, M=16): f32 out ----
__global__ void gemm2_scale_f32_kernel(const float* __restrict__ X,
                                       const float* __restrict__ Wa, const float* __restrict__ Wb,
                                       const float* __restrict__ dinva, const float* __restrict__ dinvb,
                                       float* __restrict__ ya, float* __restrict__ yb, int n) {
    constexpr int M = 16;
    __shared__ float xs[64 * LDS_XPAD];
    __shared__ float wsa[64 * M];
    __shared__ float wsb[64 * M];
    const int tid = threadIdx.x;
    const int row = tid >> 2;
    const int cg  = tid & 3;
    const int grow = blockIdx.x * 64 + row;

    {
        float4 v0, v1, v2, v3;
        if (grow < n) {
            const float4* xr = reinterpret_cast<const float4*>(X + (size_t)grow * 64 + cg * 16);
            v0 = xr[0]; v1 = xr[1]; v2 = xr[2]; v3 = xr[3];
        } else {
            v0 = v1 = v2 = v3 = make_float4(0.f, 0.f, 0.f, 0.f);
        }
        float4* xd = reinterpret_cast<float4*>(&xs[row * LDS_XPAD + cg * 16]);
        xd[0] = v0; xd[1] = v1; xd[2] = v2; xd[3] = v3;
    }
    {
        const float4* sa = reinterpret_cast<const float4*>(Wa);
        const float4* sb = reinterpret_cast<const float4*>(Wb);
        float4* da = reinterpret_cast<float4*>(wsa);
        float4* db = reinterpret_cast<float4*>(wsb);
        if (tid < 64 * M / 4) { da[tid] = sa[tid]; db[tid] = sb[tid]; }
    }
    __syncthreads();

    constexpr int CPT = 4;
    float acca[CPT], accb[CPT];
    #pragma unroll
    for (int j = 0; j < CPT; ++j) { acca[j] = 0.0f; accb[j] = 0.0f; }

    for (int k = 0; k < 64; ++k) {
        float xk = xs[row * LDS_XPAD + k];
        #pragma unroll
        for (int j = 0; j < CPT; ++j) {
            acca[j] += xk * wsa[k * M + cg * CPT + j];
            accb[j] += xk * wsb[k * M + cg * CPT + j];
        }
    }

    if (grow < n) {
        float sa = dinva[grow], sb = dinvb[grow];
        *reinterpret_cast<float4*>(ya + (size_t)grow * M + cg * CPT) =
            make_float4(acca[0] * sa, acca[1] * sa, acca[2] * sa, acca[3] * sa);
        *reinterpret_cast<float4*>(yb + (size_t)grow * M + cg * CPT) =
            make_float4(accb[0] * sb, accb[1] * sb, accb[2] * sb, accb[3] * sb);
    }
}

// ---- fused dual-relation aggregation, layer 1 (bf16 gathers, F=64) ----
// One wave per node. Cols loaded lane-parallel + shfl-broadcast.
__global__ void agg64_dual_kernel(const ushort_t* __restrict__ ya, const ushort_t* __restrict__ yb,
                                  const int* __restrict__ rp2, const int* __restrict__ col2,
                                  const float* __restrict__ dinv2,
                                  const float* __restrict__ ba, const float* __restrict__ bb,
                                  float* __restrict__ h, int n) {
    const int lane = threadIdx.x & 63;
    const int wid  = (blockIdx.x * blockDim.x + threadIdx.x) >> 6;
    const int nw   = (gridDim.x * blockDim.x) >> 6;
    const float bias = ba[lane] + bb[lane];
    for (int i = wid; i < n; i += nw) {
        float acca = bf2f(ya[(size_t)i * 64 + lane]);
        {
            const int e0 = rp2[i], e1 = rp2[i + 1];
            for (int base = e0; base < e1; base += 64) {
                const int m = min(64, e1 - base);
                int c = (lane < m) ? col2[base + lane] : 0;
                int j = 0;
                for (; j + 4 <= m; j += 4) {
                    int s0 = __shfl(c, j), s1 = __shfl(c, j + 1);
                    int s2 = __shfl(c, j + 2), s3 = __shfl(c, j + 3);
                    acca += bf2f(ya[(size_t)s0 * 64 + lane]);
                    acca += bf2f(ya[(size_t)s1 * 64 + lane]);
                    acca += bf2f(ya[(size_t)s2 * 64 + lane]);
                    acca += bf2f(ya[(size_t)s3 * 64 + lane]);
                }
                for (; j < m; ++j)
                    acca += bf2f(ya[(size_t)__shfl(c, j) * 64 + lane]);
            }
        }
        float accb = bf2f(yb[(size_t)i * 64 + lane]);
        {
            const int e0 = rp2[n + i], e1 = rp2[n + i + 1];
            for (int base = e0; base < e1; base += 64) {
                const int m = min(64, e1 - base);
                int c = (lane < m) ? col2[base + lane] : 0;
                int j = 0;
                for (; j + 4 <= m; j += 4) {
                    int s0 = __shfl(c, j), s1 = __shfl(c, j + 1);
                    int s2 = __shfl(c, j + 2), s3 = __shfl(c, j + 3);
                    accb += bf2f(yb[(size_t)s0 * 64 + lane]);
                    accb += bf2f(yb[(size_t)s1 * 64 + lane]);
                    accb += bf2f(yb[(size_t)s2 * 64 + lane]);
                    accb += bf2f(yb[(size_t)s3 * 64 + lane]);
                }
                for (; j < m; ++j)
                    accb += bf2f(yb[(size_t)__shfl(c, j) * 64 + lane]);
            }
        }
        float v = 0.5f * (acca * dinv2[i] + accb * dinv2[n + i] + bias);
        h[(size_t)i * 64 + lane] = fmaxf(v, 0.0f);
    }
}

// ---- fused dual-relation aggregation, layer 2 (f32, F=16) ----
// One wave per node: lane = 16*edge_slot + feature; 4-way edge ILP, butterfly reduce.
__global__ void agg16_dual_kernel(const float* __restrict__ za, const float* __restrict__ zb,
                                  const int* __restrict__ rp2, const int* __restrict__ col2,
                                  const float* __restrict__ dinv2,
                                  const float* __restrict__ ba, const float* __restrict__ bb,
                                  float* __restrict__ outp, int n) {
    const int lane = threadIdx.x & 63;
    const int f    = lane & 15;
    const int sub  = lane >> 4;    // 0..3
    const int wid  = (blockIdx.x * blockDim.x + threadIdx.x) >> 6;
    const int nw   = (gridDim.x * blockDim.x) >> 6;
    const float bias = ba[f] + bb[f];
    for (int i = wid; i < n; i += nw) {
        float acca = (sub == 0) ? za[(size_t)i * 16 + f] : 0.0f;
        {
            const int e0 = rp2[i], e1 = rp2[i + 1];
            for (int e = e0 + sub; e < e1; e += 4)
                acca += za[(size_t)col2[e] * 16 + f];
        }
        float accb = (sub == 0) ? zb[(size_t)i * 16 + f] : 0.0f;
        {
            const int e0 = rp2[n + i], e1 = rp2[n + i + 1];
            for (int e = e0 + sub; e < e1; e += 4)
                accb += zb[(size_t)col2[e] * 16 + f];
        }
        float v = acca * dinv2[i] + accb * dinv2[n + i];
        v += __shfl_xor(v, 16);
        v += __shfl_xor(v, 32);
        if (sub == 0) outp[(size_t)i * 16 + f] = 0.5f * (v + bias);
    }
}

extern "C" void kernel_launch(void* const* d_in, const int* in_sizes, int n_in,
                              void* d_out, int out_size, void* d_ws, size_t ws_size,
                              hipStream_t stream) {
    const float* x   = (const float*)d_in[0];
    const int*   eia = (const int*)d_in[1];
    const int*   eib = (const int*)d_in[2];
    const float* W1a = (const float*)d_in[3];
    const float* b1a = (const float*)d_in[4];
    const float* W1b = (const float*)d_in[5];
    const float* b1b = (const float*)d_in[6];
    const float* W2a = (const float*)d_in[7];
    const float* b2a = (const float*)d_in[8];
    const float* W2b = (const float*)d_in[9];
    const float* b2b = (const float*)d_in[10];
    float* out = (float*)d_out;

    const int n  = in_sizes[0] / 64;
    const int Ea = in_sizes[1] / 2;
    const int Eb = in_sizes[2] / 2;
    const int Et = Ea + Eb;
    const int n2 = 2 * n;

    // per-relation buckets <= 128 so combined <= 256 (MAXBUK)
    int shift = 9;
    while ((((long long)n + (1LL << shift) - 1) >> shift) > 128) ++shift;
    const int nbuk = (int)(((long long)n + (1LL << shift) - 1) >> shift);
    const int nbuk2 = 2 * nbuk;

    char* wsp = (char*)d_ws;
    size_t off = 0;
    auto carve = [&](size_t elems) { void* p = wsp + off; off += ((elems + 3) & ~(size_t)3) * 4; return p; };
    float* dinv2    = (float*)carve(n2);
    int*   rowptr2  = (int*)carve(n2 + 1);
    int*   deg2     = (int*)carve(n2);          // NOTE: bcnt2 carved immediately after,
    int*   bcnt2    = (int*)carve(MAXBUK);      // zeroed together with deg2 in one launch
    int*   bcursor2 = (int*)carve(MAXBUK);
    int*   cursor2  = (int*)carve(n2);
    int*   partials = (int*)carve(1024);
    int*   col2     = (int*)carve(Et);
    ushort_t* ya    = (ushort_t*)carve((size_t)32 * n);   // 64n bf16
    ushort_t* yb    = (ushort_t*)carve((size_t)32 * n);
    // big union region: pairs (2*Et words) dead before C (64n words) is first written
    size_t big_words = (size_t)2 * Et > (size_t)64 * n ? (size_t)2 * Et : (size_t)64 * n;
    void*  big      = carve(big_words);
    int2*  pairs    = (int2*)big;
    float* C        = (float*)big;
    // layer-2 projections alias ya/yb (dead after agg64)
    float* z2a = (float*)ya;
    float* z2b = (float*)yb;

    const int T = 256;
    auto cdiv = [](long long a, long long b) { return (unsigned)((a + b - 1) / b); };
    const unsigned nb = cdiv(n2, 256);

    // ---- combined CSR build (both relations) ----
    zero_int_kernel<<<cdiv(n2 + MAXBUK, T), T, 0, stream>>>(deg2, n2 + MAXBUK);
    bhist2_kernel<<<cdiv(Et, (long long)T * 16), T, 0, stream>>>(eia + Ea, eib + Eb, bcnt2, deg2,
                                                                 Ea, Et, shift, nbuk, n);
    bscan_kernel<<<1, 256, 0, stream>>>(bcnt2, bcursor2, nbuk2);
    scan1_kernel<<<nb, 256, 0, stream>>>(deg2, rowptr2, partials, n2);
    scan2_kernel<<<1, 64, 0, stream>>>(partials, nb);
    scan3_kernel<<<nb, 256, 0, stream>>>(rowptr2, partials, cursor2, deg2, dinv2, n2, Et);
    bfill2_kernel<<<cdiv(Et, BF_CHUNK), T, 0, stream>>>(eia, eib, bcursor2, pairs,
                                                        Ea, Eb, Et, shift, nbuk, n);
    lfill_kernel<<<cdiv(Et, T), T, 0, stream>>>(pairs, cursor2, col2, Et);

    const unsigned AGG_GRID = 2048;

    // ---- layer 1 ----
    gemm2_scale_bf16_kernel<<<cdiv(n, 64), T, 0, stream>>>(x, W1a, W1b, dinv2, dinv2 + n, ya, yb, n);
    agg64_dual_kernel<<<AGG_GRID, T, 0, stream>>>(ya, yb, rowptr2, col2, dinv2, b1a, b1b, C, n);

    // ---- layer 2 ----
    gemm2_scale_f32_kernel<<<cdiv(n, 64), T, 0, stream>>>(C, W2a, W2b, dinv2, dinv2 + n, z2a, z2b, n);
    agg16_dual_kernel<<<AGG_GRID, T, 0, stream>>>(z2a, z2b, rowptr2, col2, dinv2, b2a, b2b, out, n);
}

// Round 6
// 299.850 us; speedup vs baseline: 1.4732x; 1.4732x over previous
//
#include <hip/hip_runtime.h>

#define LDS_XPAD 68
#define MAXBUK 256
#define BF_CHUNK 2048

typedef unsigned short ushort_t;
typedef unsigned int uint_t;

__device__ __forceinline__ ushort_t f2bf(float x) {
    uint_t u = __float_as_uint(x);
    uint_t r = (u + 0x7FFFu + ((u >> 16) & 1u)) >> 16;
    return (ushort_t)r;
}
__device__ __forceinline__ float bf2f(ushort_t h) {
    return __uint_as_float((uint_t)h << 16);
}

__global__ void zero_int_kernel(int* p, int n) {
    int i = blockIdx.x * blockDim.x + threadIdx.x;
    if (i < n) p[i] = 0;
}

// Bucket histogram for BOTH relations in one pass (LDS-only atomics + 1 global add per bucket per block).
__global__ void bhist2_kernel(const int* __restrict__ dsta, const int* __restrict__ dstb,
                              int* __restrict__ bcnt2,
                              int Ea, int Et, int shift, int nbuk) {
    __shared__ int h[MAXBUK];
    for (int i = threadIdx.x; i < 2 * nbuk; i += blockDim.x) h[i] = 0;
    __syncthreads();
    int stride = gridDim.x * blockDim.x;
    for (int e = blockIdx.x * blockDim.x + threadIdx.x; e < Et; e += stride) {
        int rel = (e >= Ea);
        int d = rel ? dstb[e - Ea] : dsta[e];
        atomicAdd(&h[(rel ? nbuk : 0) + (d >> shift)], 1);
    }
    __syncthreads();
    for (int i = threadIdx.x; i < 2 * nbuk; i += blockDim.x)
        if (h[i]) atomicAdd(&bcnt2[i], h[i]);
}

// exclusive scan of bucket counts -> bbase (preserved) and bcursor (working copy); tail rowptr entry
__global__ void bscan_kernel(const int* __restrict__ bcnt, int* __restrict__ bbase,
                             int* __restrict__ bcursor, int nbuk2,
                             int* __restrict__ rowptr2, int n2, int Et) {
    __shared__ int s[256];
    int t = threadIdx.x;
    int v = (t < nbuk2) ? bcnt[t] : 0;
    s[t] = v;
    __syncthreads();
    #pragma unroll
    for (int d = 1; d < 256; d <<= 1) {
        int u = (t >= d) ? s[t - d] : 0;
        __syncthreads();
        s[t] += u;
        __syncthreads();
    }
    if (t < nbuk2) { int e = s[t] - v; bbase[t] = e; bcursor[t] = e; }
    if (t == 0) rowptr2[n2] = Et;
}

// Bin (src, dst2) pairs by combined bucket id, chunk-local LDS counting.
__global__ void bfill2_kernel(const int* __restrict__ eia, const int* __restrict__ eib,
                              int* __restrict__ bcursor, int2* __restrict__ pairs,
                              int Ea, int Eb, int Et, int shift, int nbuk, int n) {
    __shared__ int cnt[MAXBUK];
    __shared__ int base[MAXBUK];
    __shared__ int off[MAXBUK];
    const int t = threadIdx.x;
    const long long e0 = (long long)blockIdx.x * BF_CHUNK;
    const int nedge = (int)min((long long)BF_CHUNK, (long long)Et - e0);
    const int nbuk2 = 2 * nbuk;
    for (int i = t; i < nbuk2; i += 256) cnt[i] = 0;
    __syncthreads();
    for (int i = t; i < nedge; i += 256) {
        long long e = e0 + i;
        int rel = (e >= Ea);
        int d = rel ? eib[Eb + (e - Ea)] : eia[Ea + e];
        atomicAdd(&cnt[(rel ? nbuk : 0) + (d >> shift)], 1);
    }
    __syncthreads();
    for (int i = t; i < nbuk2; i += 256) {
        off[i] = 0;
        base[i] = cnt[i] ? atomicAdd(&bcursor[i], cnt[i]) : 0;
    }
    __syncthreads();
    for (int i = t; i < nedge; i += 256) {
        long long e = e0 + i;
        int rel = (e >= Ea);
        int s, d;
        if (rel) { s = eib[e - Ea]; d = eib[Eb + (e - Ea)]; }
        else     { s = eia[e];      d = eia[Ea + e]; }
        int b = (rel ? nbuk : 0) + (d >> shift);
        int p = base[b] + atomicAdd(&off[b], 1);
        pairs[p] = make_int2(s, (rel ? n : 0) + d);
    }
}

// Per-bucket CSR build: LDS-only node counting + scan + cursor placement.
// One 1024-thread block per combined bucket. No global atomics at all.
template<int NPB>
__global__ void bucket_csr_kernel(const int2* __restrict__ pairs,
                                  const int* __restrict__ bbase2, const int* __restrict__ bcnt2,
                                  int* __restrict__ rowptr2, float* __restrict__ dinv2,
                                  int* __restrict__ col2,
                                  int nbuk, int shift, int n) {
    constexpr int BLK = 1024;
    constexpr int K = NPB / BLK;
    __shared__ int cnt[NPB];
    __shared__ int ssum[BLK];
    const int b = blockIdx.x;
    const int t = threadIdx.x;
    const int rel = (b >= nbuk);
    const int blocal = rel ? b - nbuk : b;
    const int nodelo = blocal << shift;                 // relation-local node base
    const int node0 = (rel ? n : 0) + nodelo;           // combined node base
    const int NN = min(NPB, n - nodelo);                // nodes in this bucket
    const int p0 = bbase2[b];
    const int p1 = p0 + bcnt2[b];

    #pragma unroll
    for (int k = 0; k < K; ++k) cnt[t + k * BLK] = 0;
    __syncthreads();
    for (int idx = p0 + t; idx < p1; idx += BLK)
        atomicAdd(&cnt[pairs[idx].y - node0], 1);
    __syncthreads();

    int a[K]; int s = 0;
    #pragma unroll
    for (int k = 0; k < K; ++k) { a[k] = cnt[t * K + k]; s += a[k]; }
    ssum[t] = s;
    __syncthreads();
    #pragma unroll
    for (int d = 1; d < BLK; d <<= 1) {
        int u = (t >= d) ? ssum[t - d] : 0;
        __syncthreads();
        ssum[t] += u;
        __syncthreads();
    }
    int run = p0 + ssum[t] - s;     // exclusive prefix, absolute col position
    __syncthreads();
    #pragma unroll
    for (int k = 0; k < K; ++k) {
        int j = t * K + k;
        cnt[j] = run;               // absolute cursor
        if (j < NN) {
            rowptr2[node0 + j] = run;
            dinv2[node0 + j] = rsqrtf((float)(a[k] + 1));   // +1 = self-loop
        }
        run += a[k];
    }
    __syncthreads();
    for (int idx = p0 + t; idx < p1; idx += BLK) {
        int2 p = pairs[idx];
        int pos = atomicAdd(&cnt[p.y - node0], 1);
        col2[pos] = p.x;
    }
}

// ---- dual-weight GEMM (layer 1, M=64): ya/yb written as bf16 ----
__global__ void gemm2_scale_bf16_kernel(const float* __restrict__ X,
                                        const float* __restrict__ Wa, const float* __restrict__ Wb,
                                        const float* __restrict__ dinva, const float* __restrict__ dinvb,
                                        ushort_t* __restrict__ ya, ushort_t* __restrict__ yb, int n) {
    constexpr int M = 64;
    __shared__ float xs[64 * LDS_XPAD];
    __shared__ float wsa[64 * M];
    __shared__ float wsb[64 * M];
    const int tid = threadIdx.x;
    const int row = tid >> 2;
    const int cg  = tid & 3;
    const int grow = blockIdx.x * 64 + row;

    {
        float4 v0, v1, v2, v3;
        if (grow < n) {
            const float4* xr = reinterpret_cast<const float4*>(X + (size_t)grow * 64 + cg * 16);
            v0 = xr[0]; v1 = xr[1]; v2 = xr[2]; v3 = xr[3];
        } else {
            v0 = v1 = v2 = v3 = make_float4(0.f, 0.f, 0.f, 0.f);
        }
        float4* xd = reinterpret_cast<float4*>(&xs[row * LDS_XPAD + cg * 16]);
        xd[0] = v0; xd[1] = v1; xd[2] = v2; xd[3] = v3;
    }
    {
        const float4* sa = reinterpret_cast<const float4*>(Wa);
        const float4* sb = reinterpret_cast<const float4*>(Wb);
        float4* da = reinterpret_cast<float4*>(wsa);
        float4* db = reinterpret_cast<float4*>(wsb);
        #pragma unroll
        for (int i = 0; i < 4; ++i) {
            int idx = tid + i * 256;
            da[idx] = sa[idx]; db[idx] = sb[idx];
        }
    }
    __syncthreads();

    constexpr int CPT = 16;
    float acca[CPT], accb[CPT];
    #pragma unroll
    for (int j = 0; j < CPT; ++j) { acca[j] = 0.0f; accb[j] = 0.0f; }

    for (int k = 0; k < 64; ++k) {
        float xk = xs[row * LDS_XPAD + k];
        #pragma unroll
        for (int j = 0; j < CPT; ++j) {
            acca[j] += xk * wsa[k * M + cg * CPT + j];
            accb[j] += xk * wsb[k * M + cg * CPT + j];
        }
    }

    if (grow < n) {
        float sa = dinva[grow], sb = dinvb[grow];
        uint_t pka[8], pkb[8];
        #pragma unroll
        for (int j = 0; j < 8; ++j) {
            pka[j] = (uint_t)f2bf(acca[2 * j] * sa) | ((uint_t)f2bf(acca[2 * j + 1] * sa) << 16);
            pkb[j] = (uint_t)f2bf(accb[2 * j] * sb) | ((uint_t)f2bf(accb[2 * j + 1] * sb) << 16);
        }
        uint4* pa = reinterpret_cast<uint4*>(ya + (size_t)grow * 64 + cg * 16);
        uint4* pb = reinterpret_cast<uint4*>(yb + (size_t)grow * 64 + cg * 16);
        pa[0] = make_uint4(pka[0], pka[1], pka[2], pka[3]);
        pa[1] = make_uint4(pka[4], pka[5], pka[6], pka[7]);
        pb[0] = make_uint4(pkb[0], pkb[1], pkb[2], pkb[3]);
        pb[1] = make_uint4(pkb[4], pkb[5], pkb[6], pkb[7]);
    }
}

// ---- dual-weight GEMM (layer 2, M=16): f32 out ----
__global__ void gemm2_scale_f32_kernel(const float* __restrict__ X,
                                       const float* __restrict__ Wa, const float* __restrict__ Wb,
                                       const float* __restrict__ dinva, const float* __restrict__ dinvb,
                                       float* __restrict__ ya, float* __restrict__ yb, int n) {
    constexpr int M = 16;
    __shared__ float xs[64 * LDS_XPAD];
    __shared__ float wsa[64 * M];
    __shared__ float wsb[64 * M];
    const int tid = threadIdx.x;
    const int row = tid >> 2;
    const int cg  = tid & 3;
    const int grow = blockIdx.x * 64 + row;

    {
        float4 v0, v1, v2, v3;
        if (grow < n) {
            const float4* xr = reinterpret_cast<const float4*>(X + (size_t)grow * 64 + cg * 16);
            v0 = xr[0]; v1 = xr[1]; v2 = xr[2]; v3 = xr[3];
        } else {
            v0 = v1 = v2 = v3 = make_float4(0.f, 0.f, 0.f, 0.f);
        }
        float4* xd = reinterpret_cast<float4*>(&xs[row * LDS_XPAD + cg * 16]);
        xd[0] = v0; xd[1] = v1; xd[2] = v2; xd[3] = v3;
    }
    {
        const float4* sa = reinterpret_cast<const float4*>(Wa);
        const float4* sb = reinterpret_cast<const float4*>(Wb);
        float4* da = reinterpret_cast<float4*>(wsa);
        float4* db = reinterpret_cast<float4*>(wsb);
        if (tid < 64 * M / 4) { da[tid] = sa[tid]; db[tid] = sb[tid]; }
    }
    __syncthreads();

    constexpr int CPT = 4;
    float acca[CPT], accb[CPT];
    #pragma unroll
    for (int j = 0; j < CPT; ++j) { acca[j] = 0.0f; accb[j] = 0.0f; }

    for (int k = 0; k < 64; ++k) {
        float xk = xs[row * LDS_XPAD + k];
        #pragma unroll
        for (int j = 0; j < CPT; ++j) {
            acca[j] += xk * wsa[k * M + cg * CPT + j];
            accb[j] += xk * wsb[k * M + cg * CPT + j];
        }
    }

    if (grow < n) {
        float sa = dinva[grow], sb = dinvb[grow];
        *reinterpret_cast<float4*>(ya + (size_t)grow * M + cg * CPT) =
            make_float4(acca[0] * sa, acca[1] * sa, acca[2] * sa, acca[3] * sa);
        *reinterpret_cast<float4*>(yb + (size_t)grow * M + cg * CPT) =
            make_float4(accb[0] * sb, accb[1] * sb, accb[2] * sb, accb[3] * sb);
    }
}

// ---- fused dual-relation aggregation, layer 1 (bf16 gathers, F=64) ----
__global__ void agg64_dual_kernel(const ushort_t* __restrict__ ya, const ushort_t* __restrict__ yb,
                                  const int* __restrict__ rp2, const int* __restrict__ col2,
                                  const float* __restrict__ dinv2,
                                  const float* __restrict__ ba, const float* __restrict__ bb,
                                  float* __restrict__ h, int n) {
    const int lane = threadIdx.x & 63;
    const int wid  = (blockIdx.x * blockDim.x + threadIdx.x) >> 6;
    const int nw   = (gridDim.x * blockDim.x) >> 6;
    const float bias = ba[lane] + bb[lane];
    for (int i = wid; i < n; i += nw) {
        float acca = bf2f(ya[(size_t)i * 64 + lane]);
        {
            const int e0 = rp2[i], e1 = rp2[i + 1];
            for (int base = e0; base < e1; base += 64) {
                const int m = min(64, e1 - base);
                int c = (lane < m) ? col2[base + lane] : 0;
                int j = 0;
                for (; j + 4 <= m; j += 4) {
                    int s0 = __shfl(c, j), s1 = __shfl(c, j + 1);
                    int s2 = __shfl(c, j + 2), s3 = __shfl(c, j + 3);
                    acca += bf2f(ya[(size_t)s0 * 64 + lane]);
                    acca += bf2f(ya[(size_t)s1 * 64 + lane]);
                    acca += bf2f(ya[(size_t)s2 * 64 + lane]);
                    acca += bf2f(ya[(size_t)s3 * 64 + lane]);
                }
                for (; j < m; ++j)
                    acca += bf2f(ya[(size_t)__shfl(c, j) * 64 + lane]);
            }
        }
        float accb = bf2f(yb[(size_t)i * 64 + lane]);
        {
            const int e0 = rp2[n + i], e1 = rp2[n + i + 1];
            for (int base = e0; base < e1; base += 64) {
                const int m = min(64, e1 - base);
                int c = (lane < m) ? col2[base + lane] : 0;
                int j = 0;
                for (; j + 4 <= m; j += 4) {
                    int s0 = __shfl(c, j), s1 = __shfl(c, j + 1);
                    int s2 = __shfl(c, j + 2), s3 = __shfl(c, j + 3);
                    accb += bf2f(yb[(size_t)s0 * 64 + lane]);
                    accb += bf2f(yb[(size_t)s1 * 64 + lane]);
                    accb += bf2f(yb[(size_t)s2 * 64 + lane]);
                    accb += bf2f(yb[(size_t)s3 * 64 + lane]);
                }
                for (; j < m; ++j)
                    accb += bf2f(yb[(size_t)__shfl(c, j) * 64 + lane]);
            }
        }
        float v = 0.5f * (acca * dinv2[i] + accb * dinv2[n + i] + bias);
        h[(size_t)i * 64 + lane] = fmaxf(v, 0.0f);
    }
}

// ---- fused dual-relation aggregation, layer 2 (f32, F=16) ----
__global__ void agg16_dual_kernel(const float* __restrict__ za, const float* __restrict__ zb,
                                  const int* __restrict__ rp2, const int* __restrict__ col2,
                                  const float* __restrict__ dinv2,
                                  const float* __restrict__ ba, const float* __restrict__ bb,
                                  float* __restrict__ outp, int n) {
    const int lane = threadIdx.x & 63;
    const int f    = lane & 15;
    const int sub  = lane >> 4;    // 0..3
    const int wid  = (blockIdx.x * blockDim.x + threadIdx.x) >> 6;
    const int nw   = (gridDim.x * blockDim.x) >> 6;
    const float bias = ba[f] + bb[f];
    for (int i = wid; i < n; i += nw) {
        float acca = (sub == 0) ? za[(size_t)i * 16 + f] : 0.0f;
        {
            const int e0 = rp2[i], e1 = rp2[i + 1];
            for (int e = e0 + sub; e < e1; e += 4)
                acca += za[(size_t)col2[e] * 16 + f];
        }
        float accb = (sub == 0) ? zb[(size_t)i * 16 + f] : 0.0f;
        {
            const int e0 = rp2[n + i], e1 = rp2[n + i + 1];
            for (int e = e0 + sub; e < e1; e += 4)
                accb += zb[(size_t)col2[e] * 16 + f];
        }
        float v = acca * dinv2[i] + accb * dinv2[n + i];
        v += __shfl_xor(v, 16);
        v += __shfl_xor(v, 32);
        if (sub == 0) outp[(size_t)i * 16 + f] = 0.5f * (v + bias);
    }
}

extern "C" void kernel_launch(void* const* d_in, const int* in_sizes, int n_in,
                              void* d_out, int out_size, void* d_ws, size_t ws_size,
                              hipStream_t stream) {
    const float* x   = (const float*)d_in[0];
    const int*   eia = (const int*)d_in[1];
    const int*   eib = (const int*)d_in[2];
    const float* W1a = (const float*)d_in[3];
    const float* b1a = (const float*)d_in[4];
    const float* W1b = (const float*)d_in[5];
    const float* b1b = (const float*)d_in[6];
    const float* W2a = (const float*)d_in[7];
    const float* b2a = (const float*)d_in[8];
    const float* W2b = (const float*)d_in[9];
    const float* b2b = (const float*)d_in[10];
    float* out = (float*)d_out;

    const int n  = in_sizes[0] / 64;
    const int Ea = in_sizes[1] / 2;
    const int Eb = in_sizes[2] / 2;
    const int Et = Ea + Eb;
    const int n2 = 2 * n;

    // nodes-per-bucket 2^shift; per-relation buckets <= 128 so combined <= 256 (MAXBUK)
    int shift = 10;
    while ((((long long)n + (1LL << shift) - 1) >> shift) > 128) ++shift;
    const int nbuk = (int)(((long long)n + (1LL << shift) - 1) >> shift);
    const int nbuk2 = 2 * nbuk;

    char* wsp = (char*)d_ws;
    size_t off = 0;
    auto carve = [&](size_t elems) { void* p = wsp + off; off += ((elems + 3) & ~(size_t)3) * 4; return p; };
    float* dinv2    = (float*)carve(n2);
    int*   rowptr2  = (int*)carve(n2 + 1);
    int*   bcnt2    = (int*)carve(MAXBUK);
    int*   bbase2   = (int*)carve(MAXBUK);
    int*   bcursor2 = (int*)carve(MAXBUK);
    int*   col2     = (int*)carve(Et);
    ushort_t* ya    = (ushort_t*)carve((size_t)32 * n);   // 64n bf16
    ushort_t* yb    = (ushort_t*)carve((size_t)32 * n);
    // big union region: pairs (2*Et words) dead before C (64n words) is first written
    size_t big_words = (size_t)2 * Et > (size_t)64 * n ? (size_t)2 * Et : (size_t)64 * n;
    void*  big      = carve(big_words);
    int2*  pairs    = (int2*)big;
    float* C        = (float*)big;
    // layer-2 projections alias ya/yb (dead after agg64)
    float* z2a = (float*)ya;
    float* z2b = (float*)yb;

    const int T = 256;
    auto cdiv = [](long long a, long long b) { return (unsigned)((a + b - 1) / b); };

    // ---- combined CSR build, zero global atomics on node-sized arrays ----
    zero_int_kernel<<<1, 256, 0, stream>>>(bcnt2, MAXBUK);
    bhist2_kernel<<<cdiv(Et, (long long)T * 16), T, 0, stream>>>(eia + Ea, eib + Eb, bcnt2,
                                                                 Ea, Et, shift, nbuk);
    bscan_kernel<<<1, 256, 0, stream>>>(bcnt2, bbase2, bcursor2, nbuk2, rowptr2, n2, Et);
    bfill2_kernel<<<cdiv(Et, BF_CHUNK), T, 0, stream>>>(eia, eib, bcursor2, pairs,
                                                        Ea, Eb, Et, shift, nbuk, n);
    if (shift == 10)
        bucket_csr_kernel<1024><<<nbuk2, 1024, 0, stream>>>(pairs, bbase2, bcnt2, rowptr2, dinv2,
                                                            col2, nbuk, shift, n);
    else if (shift == 11)
        bucket_csr_kernel<2048><<<nbuk2, 1024, 0, stream>>>(pairs, bbase2, bcnt2, rowptr2, dinv2,
                                                            col2, nbuk, shift, n);
    else
        bucket_csr_kernel<4096><<<nbuk2, 1024, 0, stream>>>(pairs, bbase2, bcnt2, rowptr2, dinv2,
                                                            col2, nbuk, shift, n);

    const unsigned AGG_GRID = 2048;

    // ---- layer 1 ----
    gemm2_scale_bf16_kernel<<<cdiv(n, 64), T, 0, stream>>>(x, W1a, W1b, dinv2, dinv2 + n, ya, yb, n);
    agg64_dual_kernel<<<AGG_GRID, T, 0, stream>>>(ya, yb, rowptr2, col2, dinv2, b1a, b1b, C, n);

    // ---- layer 2 ----
    gemm2_scale_f32_kernel<<<cdiv(n, 64), T, 0, stream>>>(C, W2a, W2b, dinv2, dinv2 + n, z2a, z2b, n);
    agg16_dual_kernel<<<AGG_GRID, T, 0, stream>>>(z2a, z2b, rowptr2, col2, dinv2, b2a, b2b, out, n);
}

// Round 7
// 259.272 us; speedup vs baseline: 1.7038x; 1.1565x over previous
//
#include <hip/hip_runtime.h>

#define LDS_XPAD 68
#define XS_STRIDE 72
#define MAXBUK 256
#define BF_CHUNK 2048

typedef unsigned short ushort_t;
typedef unsigned int uint_t;
typedef __attribute__((ext_vector_type(8))) short short8_t;
typedef __attribute__((ext_vector_type(4))) float f32x4;

__device__ __forceinline__ ushort_t f2bf(float x) {
    uint_t u = __float_as_uint(x);
    uint_t r = (u + 0x7FFFu + ((u >> 16) & 1u)) >> 16;
    return (ushort_t)r;
}
__device__ __forceinline__ float bf2f(ushort_t h) {
    return __uint_as_float((uint_t)h << 16);
}

__global__ void zero_int_kernel(int* p, int n) {
    int i = blockIdx.x * blockDim.x + threadIdx.x;
    if (i < n) p[i] = 0;
}

// Bucket histogram for BOTH relations in one pass (LDS atomics + 1 global add per bucket per block).
__global__ void bhist2_kernel(const int* __restrict__ dsta, const int* __restrict__ dstb,
                              int* __restrict__ bcnt2,
                              int Ea, int Et, int shift, int nbuk) {
    __shared__ int h[MAXBUK];
    for (int i = threadIdx.x; i < 2 * nbuk; i += blockDim.x) h[i] = 0;
    __syncthreads();
    int stride = gridDim.x * blockDim.x;
    for (int e = blockIdx.x * blockDim.x + threadIdx.x; e < Et; e += stride) {
        int rel = (e >= Ea);
        int d = rel ? dstb[e - Ea] : dsta[e];
        atomicAdd(&h[(rel ? nbuk : 0) + (d >> shift)], 1);
    }
    __syncthreads();
    for (int i = threadIdx.x; i < 2 * nbuk; i += blockDim.x)
        if (h[i]) atomicAdd(&bcnt2[i], h[i]);
}

__global__ void bscan_kernel(const int* __restrict__ bcnt, int* __restrict__ bbase,
                             int* __restrict__ bcursor, int nbuk2,
                             int* __restrict__ rowptr2, int n2, int Et) {
    __shared__ int s[256];
    int t = threadIdx.x;
    int v = (t < nbuk2) ? bcnt[t] : 0;
    s[t] = v;
    __syncthreads();
    #pragma unroll
    for (int d = 1; d < 256; d <<= 1) {
        int u = (t >= d) ? s[t - d] : 0;
        __syncthreads();
        s[t] += u;
        __syncthreads();
    }
    if (t < nbuk2) { int e = s[t] - v; bbase[t] = e; bcursor[t] = e; }
    if (t == 0) rowptr2[n2] = Et;
}

// Bin (src, dst2) pairs by combined bucket id, chunk-local LDS counting.
__global__ void bfill2_kernel(const int* __restrict__ eia, const int* __restrict__ eib,
                              int* __restrict__ bcursor, int2* __restrict__ pairs,
                              int Ea, int Eb, int Et, int shift, int nbuk, int n) {
    __shared__ int cnt[MAXBUK];
    __shared__ int base[MAXBUK];
    __shared__ int off[MAXBUK];
    const int t = threadIdx.x;
    const long long e0 = (long long)blockIdx.x * BF_CHUNK;
    const int nedge = (int)min((long long)BF_CHUNK, (long long)Et - e0);
    const int nbuk2 = 2 * nbuk;
    for (int i = t; i < nbuk2; i += 256) cnt[i] = 0;
    __syncthreads();
    for (int i = t; i < nedge; i += 256) {
        long long e = e0 + i;
        int rel = (e >= Ea);
        int d = rel ? eib[Eb + (e - Ea)] : eia[Ea + e];
        atomicAdd(&cnt[(rel ? nbuk : 0) + (d >> shift)], 1);
    }
    __syncthreads();
    for (int i = t; i < nbuk2; i += 256) {
        off[i] = 0;
        base[i] = cnt[i] ? atomicAdd(&bcursor[i], cnt[i]) : 0;
    }
    __syncthreads();
    for (int i = t; i < nedge; i += 256) {
        long long e = e0 + i;
        int rel = (e >= Ea);
        int s, d;
        if (rel) { s = eib[e - Ea]; d = eib[Eb + (e - Ea)]; }
        else     { s = eia[e];      d = eia[Ea + e]; }
        int b = (rel ? nbuk : 0) + (d >> shift);
        int p = base[b] + atomicAdd(&off[b], 1);
        pairs[p] = make_int2(s, (rel ? n : 0) + d);
    }
}

// Per-bucket CSR build: LDS-only node counting + scan + cursor placement.
template<int NPB>
__global__ void bucket_csr_kernel(const int2* __restrict__ pairs,
                                  const int* __restrict__ bbase2, const int* __restrict__ bcnt2,
                                  int* __restrict__ rowptr2, float* __restrict__ dinv2,
                                  int* __restrict__ col2,
                                  int nbuk, int shift, int n) {
    constexpr int BLK = 1024;
    constexpr int K = NPB / BLK;
    __shared__ int cnt[NPB];
    __shared__ int ssum[BLK];
    const int b = blockIdx.x;
    const int t = threadIdx.x;
    const int rel = (b >= nbuk);
    const int blocal = rel ? b - nbuk : b;
    const int nodelo = blocal << shift;
    const int node0 = (rel ? n : 0) + nodelo;
    const int NN = min(NPB, n - nodelo);
    const int p0 = bbase2[b];
    const int p1 = p0 + bcnt2[b];

    #pragma unroll
    for (int k = 0; k < K; ++k) cnt[t + k * BLK] = 0;
    __syncthreads();
    for (int idx = p0 + t; idx < p1; idx += BLK)
        atomicAdd(&cnt[pairs[idx].y - node0], 1);
    __syncthreads();

    int a[K]; int s = 0;
    #pragma unroll
    for (int k = 0; k < K; ++k) { a[k] = cnt[t * K + k]; s += a[k]; }
    ssum[t] = s;
    __syncthreads();
    #pragma unroll
    for (int d = 1; d < BLK; d <<= 1) {
        int u = (t >= d) ? ssum[t - d] : 0;
        __syncthreads();
        ssum[t] += u;
        __syncthreads();
    }
    int run = p0 + ssum[t] - s;
    __syncthreads();
    #pragma unroll
    for (int k = 0; k < K; ++k) {
        int j = t * K + k;
        cnt[j] = run;
        if (j < NN) {
            rowptr2[node0 + j] = run;
            dinv2[node0 + j] = rsqrtf((float)(a[k] + 1));
        }
        run += a[k];
    }
    __syncthreads();
    for (int idx = p0 + t; idx < p1; idx += BLK) {
        int2 p = pairs[idx];
        int pos = atomicAdd(&cnt[p.y - node0], 1);
        col2[pos] = p.x;
    }
}

// ---- MFMA dual-weight GEMM (layer 1): ya|yb = (Xbf16 @ [Wa|Wb]) * dinv, bf16 out ----
// 256 threads = 4 waves; block computes 64 rows x 128 cols, K=64.
__global__ void gemm2_mfma_bf16_kernel(const float* __restrict__ X,
                                       const float* __restrict__ Wa, const float* __restrict__ Wb,
                                       const float* __restrict__ dinva, const float* __restrict__ dinvb,
                                       ushort_t* __restrict__ ya, ushort_t* __restrict__ yb, int n) {
    __shared__ ushort_t Xs[64 * XS_STRIDE];          // rows x K, bf16, padded stride
    __shared__ ushort_t Wt[128 * XS_STRIDE];         // out-col x K (transposed), bf16
    const int tid = threadIdx.x;
    const int rowbase = blockIdx.x * 64;

    // stage X (f32 -> bf16), row-major
    {
        int row = tid >> 2, cg = tid & 3;
        int grow = rowbase + row;
        float4 v[4];
        if (grow < n) {
            const float4* xr = reinterpret_cast<const float4*>(X + (size_t)grow * 64 + cg * 16);
            v[0] = xr[0]; v[1] = xr[1]; v[2] = xr[2]; v[3] = xr[3];
        } else {
            v[0] = v[1] = v[2] = v[3] = make_float4(0.f, 0.f, 0.f, 0.f);
        }
        ushort_t* dst = &Xs[row * XS_STRIDE + cg * 16];
        #pragma unroll
        for (int q = 0; q < 4; ++q) {
            dst[q * 4 + 0] = f2bf(v[q].x); dst[q * 4 + 1] = f2bf(v[q].y);
            dst[q * 4 + 2] = f2bf(v[q].z); dst[q * 4 + 3] = f2bf(v[q].w);
        }
    }
    // stage W transposed: Wt[c][k] = W[k][c]
    for (int idx = tid; idx < 4096; idx += 256) {
        int k = idx >> 6, c = idx & 63;
        Wt[c * XS_STRIDE + k] = f2bf(Wa[idx]);
        Wt[(64 + c) * XS_STRIDE + k] = f2bf(Wb[idx]);
    }
    __syncthreads();

    const int wid = tid >> 6, lane = tid & 63;
    const int lrow = lane & 15;
    const int lk = (lane >> 4) * 8;      // K-offset for A/B fragments

    short8_t a0 = *reinterpret_cast<const short8_t*>(&Xs[(wid * 16 + lrow) * XS_STRIDE + lk]);
    short8_t a1 = *reinterpret_cast<const short8_t*>(&Xs[(wid * 16 + lrow) * XS_STRIDE + 32 + lk]);

    f32x4 acc[8];
    #pragma unroll
    for (int ct = 0; ct < 8; ++ct) {
        short8_t b0 = *reinterpret_cast<const short8_t*>(&Wt[(ct * 16 + lrow) * XS_STRIDE + lk]);
        short8_t b1 = *reinterpret_cast<const short8_t*>(&Wt[(ct * 16 + lrow) * XS_STRIDE + 32 + lk]);
        f32x4 c = {0.f, 0.f, 0.f, 0.f};
        c = __builtin_amdgcn_mfma_f32_16x16x32_bf16(a0, b0, c, 0, 0, 0);
        c = __builtin_amdgcn_mfma_f32_16x16x32_bf16(a1, b1, c, 0, 0, 0);
        acc[ct] = c;
    }

    // C/D layout: col = lane&15, row = (lane>>4)*4 + r
    const int rq = (lane >> 4) * 4;
    #pragma unroll
    for (int r = 0; r < 4; ++r) {
        int grow = rowbase + wid * 16 + rq + r;
        if (grow < n) {
            float sa = dinva[grow], sb = dinvb[grow];
            #pragma unroll
            for (int ct = 0; ct < 8; ++ct) {
                int col = ct * 16 + lrow;
                float v = acc[ct][r];
                if (col < 64) ya[(size_t)grow * 64 + col] = f2bf(v * sa);
                else          yb[(size_t)grow * 64 + (col - 64)] = f2bf(v * sb);
            }
        }
    }
}

// ---- dual-weight GEMM (layer 2, M=16): bf16 out ----
__global__ void gemm2_scale_f32_kernel(const float* __restrict__ X,
                                       const float* __restrict__ Wa, const float* __restrict__ Wb,
                                       const float* __restrict__ dinva, const float* __restrict__ dinvb,
                                       ushort_t* __restrict__ ya, ushort_t* __restrict__ yb, int n) {
    constexpr int M = 16;
    __shared__ float xs[64 * LDS_XPAD];
    __shared__ float wsa[64 * M];
    __shared__ float wsb[64 * M];
    const int tid = threadIdx.x;
    const int row = tid >> 2;
    const int cg  = tid & 3;
    const int grow = blockIdx.x * 64 + row;

    {
        float4 v0, v1, v2, v3;
        if (grow < n) {
            const float4* xr = reinterpret_cast<const float4*>(X + (size_t)grow * 64 + cg * 16);
            v0 = xr[0]; v1 = xr[1]; v2 = xr[2]; v3 = xr[3];
        } else {
            v0 = v1 = v2 = v3 = make_float4(0.f, 0.f, 0.f, 0.f);
        }
        float4* xd = reinterpret_cast<float4*>(&xs[row * LDS_XPAD + cg * 16]);
        xd[0] = v0; xd[1] = v1; xd[2] = v2; xd[3] = v3;
    }
    {
        const float4* sa = reinterpret_cast<const float4*>(Wa);
        const float4* sb = reinterpret_cast<const float4*>(Wb);
        float4* da = reinterpret_cast<float4*>(wsa);
        float4* db = reinterpret_cast<float4*>(wsb);
        if (tid < 64 * M / 4) { da[tid] = sa[tid]; db[tid] = sb[tid]; }
    }
    __syncthreads();

    constexpr int CPT = 4;
    float acca[CPT], accb[CPT];
    #pragma unroll
    for (int j = 0; j < CPT; ++j) { acca[j] = 0.0f; accb[j] = 0.0f; }

    for (int k = 0; k < 64; ++k) {
        float xk = xs[row * LDS_XPAD + k];
        #pragma unroll
        for (int j = 0; j < CPT; ++j) {
            acca[j] += xk * wsa[k * M + cg * CPT + j];
            accb[j] += xk * wsb[k * M + cg * CPT + j];
        }
    }

    if (grow < n) {
        float sa = dinva[grow], sb = dinvb[grow];
        uint2 pa, pb;
        pa.x = (uint_t)f2bf(acca[0] * sa) | ((uint_t)f2bf(acca[1] * sa) << 16);
        pa.y = (uint_t)f2bf(acca[2] * sa) | ((uint_t)f2bf(acca[3] * sa) << 16);
        pb.x = (uint_t)f2bf(accb[0] * sb) | ((uint_t)f2bf(accb[1] * sb) << 16);
        pb.y = (uint_t)f2bf(accb[2] * sb) | ((uint_t)f2bf(accb[3] * sb) << 16);
        *reinterpret_cast<uint2*>(ya + (size_t)grow * M + cg * CPT) = pa;
        *reinterpret_cast<uint2*>(yb + (size_t)grow * M + cg * CPT) = pb;
    }
}

// ---- fused dual-relation aggregation, layer 1 (bf16 gathers, F=64) ----
__global__ void agg64_dual_kernel(const ushort_t* __restrict__ ya, const ushort_t* __restrict__ yb,
                                  const int* __restrict__ rp2, const int* __restrict__ col2,
                                  const float* __restrict__ dinv2,
                                  const float* __restrict__ ba, const float* __restrict__ bb,
                                  float* __restrict__ h, int n) {
    const int lane = threadIdx.x & 63;
    const int wid  = (blockIdx.x * blockDim.x + threadIdx.x) >> 6;
    const int nw   = (gridDim.x * blockDim.x) >> 6;
    const float bias = ba[lane] + bb[lane];
    for (int i = wid; i < n; i += nw) {
        float acca = bf2f(ya[(size_t)i * 64 + lane]);
        {
            const int e0 = rp2[i], e1 = rp2[i + 1];
            for (int base = e0; base < e1; base += 64) {
                const int m = min(64, e1 - base);
                int c = (lane < m) ? col2[base + lane] : 0;
                int j = 0;
                for (; j + 4 <= m; j += 4) {
                    int s0 = __shfl(c, j), s1 = __shfl(c, j + 1);
                    int s2 = __shfl(c, j + 2), s3 = __shfl(c, j + 3);
                    acca += bf2f(ya[(size_t)s0 * 64 + lane]);
                    acca += bf2f(ya[(size_t)s1 * 64 + lane]);
                    acca += bf2f(ya[(size_t)s2 * 64 + lane]);
                    acca += bf2f(ya[(size_t)s3 * 64 + lane]);
                }
                for (; j < m; ++j)
                    acca += bf2f(ya[(size_t)__shfl(c, j) * 64 + lane]);
            }
        }
        float accb = bf2f(yb[(size_t)i * 64 + lane]);
        {
            const int e0 = rp2[n + i], e1 = rp2[n + i + 1];
            for (int base = e0; base < e1; base += 64) {
                const int m = min(64, e1 - base);
                int c = (lane < m) ? col2[base + lane] : 0;
                int j = 0;
                for (; j + 4 <= m; j += 4) {
                    int s0 = __shfl(c, j), s1 = __shfl(c, j + 1);
                    int s2 = __shfl(c, j + 2), s3 = __shfl(c, j + 3);
                    accb += bf2f(yb[(size_t)s0 * 64 + lane]);
                    accb += bf2f(yb[(size_t)s1 * 64 + lane]);
                    accb += bf2f(yb[(size_t)s2 * 64 + lane]);
                    accb += bf2f(yb[(size_t)s3 * 64 + lane]);
                }
                for (; j < m; ++j)
                    accb += bf2f(yb[(size_t)__shfl(c, j) * 64 + lane]);
            }
        }
        float v = 0.5f * (acca * dinv2[i] + accb * dinv2[n + i] + bias);
        h[(size_t)i * 64 + lane] = fmaxf(v, 0.0f);
    }
}

// ---- fused dual-relation aggregation, layer 2 (bf16 gathers, F=16) ----
__global__ void agg16_dual_kernel(const ushort_t* __restrict__ za, const ushort_t* __restrict__ zb,
                                  const int* __restrict__ rp2, const int* __restrict__ col2,
                                  const float* __restrict__ dinv2,
                                  const float* __restrict__ ba, const float* __restrict__ bb,
                                  float* __restrict__ outp, int n) {
    const int lane = threadIdx.x & 63;
    const int f    = lane & 15;
    const int sub  = lane >> 4;
    const int wid  = (blockIdx.x * blockDim.x + threadIdx.x) >> 6;
    const int nw   = (gridDim.x * blockDim.x) >> 6;
    const float bias = ba[f] + bb[f];
    for (int i = wid; i < n; i += nw) {
        float acca = (sub == 0) ? bf2f(za[(size_t)i * 16 + f]) : 0.0f;
        {
            const int e0 = rp2[i], e1 = rp2[i + 1];
            for (int e = e0 + sub; e < e1; e += 4)
                acca += bf2f(za[(size_t)col2[e] * 16 + f]);
        }
        float accb = (sub == 0) ? bf2f(zb[(size_t)i * 16 + f]) : 0.0f;
        {
            const int e0 = rp2[n + i], e1 = rp2[n + i + 1];
            for (int e = e0 + sub; e < e1; e += 4)
                accb += bf2f(zb[(size_t)col2[e] * 16 + f]);
        }
        float v = acca * dinv2[i] + accb * dinv2[n + i];
        v += __shfl_xor(v, 16);
        v += __shfl_xor(v, 32);
        if (sub == 0) outp[(size_t)i * 16 + f] = 0.5f * (v + bias);
    }
}

extern "C" void kernel_launch(void* const* d_in, const int* in_sizes, int n_in,
                              void* d_out, int out_size, void* d_ws, size_t ws_size,
                              hipStream_t stream) {
    const float* x   = (const float*)d_in[0];
    const int*   eia = (const int*)d_in[1];
    const int*   eib = (const int*)d_in[2];
    const float* W1a = (const float*)d_in[3];
    const float* b1a = (const float*)d_in[4];
    const float* W1b = (const float*)d_in[5];
    const float* b1b = (const float*)d_in[6];
    const float* W2a = (const float*)d_in[7];
    const float* b2a = (const float*)d_in[8];
    const float* W2b = (const float*)d_in[9];
    const float* b2b = (const float*)d_in[10];
    float* out = (float*)d_out;

    const int n  = in_sizes[0] / 64;
    const int Ea = in_sizes[1] / 2;
    const int Eb = in_sizes[2] / 2;
    const int Et = Ea + Eb;
    const int n2 = 2 * n;

    int shift = 10;
    while ((((long long)n + (1LL << shift) - 1) >> shift) > 128) ++shift;
    const int nbuk = (int)(((long long)n + (1LL << shift) - 1) >> shift);
    const int nbuk2 = 2 * nbuk;

    char* wsp = (char*)d_ws;
    size_t off = 0;
    auto carve = [&](size_t elems) { void* p = wsp + off; off += ((elems + 3) & ~(size_t)3) * 4; return p; };
    float* dinv2    = (float*)carve(n2);
    int*   rowptr2  = (int*)carve(n2 + 1);
    int*   bcnt2    = (int*)carve(MAXBUK);
    int*   bbase2   = (int*)carve(MAXBUK);
    int*   bcursor2 = (int*)carve(MAXBUK);
    int*   col2     = (int*)carve(Et);
    ushort_t* ya    = (ushort_t*)carve((size_t)32 * n);   // 64n bf16
    ushort_t* yb    = (ushort_t*)carve((size_t)32 * n);
    size_t big_words = (size_t)2 * Et > (size_t)64 * n ? (size_t)2 * Et : (size_t)64 * n;
    void*  big      = carve(big_words);
    int2*  pairs    = (int2*)big;
    float* C        = (float*)big;
    // layer-2 bf16 projections alias ya/yb (dead after agg64)
    ushort_t* z2a = ya;
    ushort_t* z2b = yb;

    const int T = 256;
    auto cdiv = [](long long a, long long b) { return (unsigned)((a + b - 1) / b); };

    // ---- combined CSR build ----
    zero_int_kernel<<<1, 256, 0, stream>>>(bcnt2, MAXBUK);
    bhist2_kernel<<<cdiv(Et, (long long)T * 16), T, 0, stream>>>(eia + Ea, eib + Eb, bcnt2,
                                                                 Ea, Et, shift, nbuk);
    bscan_kernel<<<1, 256, 0, stream>>>(bcnt2, bbase2, bcursor2, nbuk2, rowptr2, n2, Et);
    bfill2_kernel<<<cdiv(Et, BF_CHUNK), T, 0, stream>>>(eia, eib, bcursor2, pairs,
                                                        Ea, Eb, Et, shift, nbuk, n);
    if (shift == 10)
        bucket_csr_kernel<1024><<<nbuk2, 1024, 0, stream>>>(pairs, bbase2, bcnt2, rowptr2, dinv2,
                                                            col2, nbuk, shift, n);
    else if (shift == 11)
        bucket_csr_kernel<2048><<<nbuk2, 1024, 0, stream>>>(pairs, bbase2, bcnt2, rowptr2, dinv2,
                                                            col2, nbuk, shift, n);
    else
        bucket_csr_kernel<4096><<<nbuk2, 1024, 0, stream>>>(pairs, bbase2, bcnt2, rowptr2, dinv2,
                                                            col2, nbuk, shift, n);

    const unsigned AGG_GRID = 2048;

    // ---- layer 1 ----
    gemm2_mfma_bf16_kernel<<<cdiv(n, 64), T, 0, stream>>>(x, W1a, W1b, dinv2, dinv2 + n, ya, yb, n);
    agg64_dual_kernel<<<AGG_GRID, T, 0, stream>>>(ya, yb, rowptr2, col2, dinv2, b1a, b1b, C, n);

    // ---- layer 2 ----
    gemm2_scale_f32_kernel<<<cdiv(n, 64), T, 0, stream>>>(C, W2a, W2b, dinv2, dinv2 + n, z2a, z2b, n);
    agg16_dual_kernel<<<AGG_GRID, T, 0, stream>>>(z2a, z2b, rowptr2, col2, dinv2, b2a, b2b, out, n);
}

// Round 8
// 257.475 us; speedup vs baseline: 1.7157x; 1.0070x over previous
//
#include <hip/hip_runtime.h>

#define XS_STRIDE 72
#define MAXBUK 256
#define BF_CHUNK 2048

typedef unsigned short ushort_t;
typedef unsigned int uint_t;
typedef __attribute__((ext_vector_type(8))) short short8_t;
typedef __attribute__((ext_vector_type(4))) float f32x4;

__device__ __forceinline__ ushort_t f2bf(float x) {
    uint_t u = __float_as_uint(x);
    uint_t r = (u + 0x7FFFu + ((u >> 16) & 1u)) >> 16;
    return (ushort_t)r;
}
__device__ __forceinline__ float bf2f(ushort_t h) {
    return __uint_as_float((uint_t)h << 16);
}

__global__ void zero_int_kernel(int* p, int n) {
    int i = blockIdx.x * blockDim.x + threadIdx.x;
    if (i < n) p[i] = 0;
}

// Bucket histogram for BOTH relations in one pass (LDS atomics + 1 global add per bucket per block).
__global__ void bhist2_kernel(const int* __restrict__ dsta, const int* __restrict__ dstb,
                              int* __restrict__ bcnt2,
                              int Ea, int Et, int shift, int nbuk) {
    __shared__ int h[MAXBUK];
    for (int i = threadIdx.x; i < 2 * nbuk; i += blockDim.x) h[i] = 0;
    __syncthreads();
    int stride = gridDim.x * blockDim.x;
    for (int e = blockIdx.x * blockDim.x + threadIdx.x; e < Et; e += stride) {
        int rel = (e >= Ea);
        int d = rel ? dstb[e - Ea] : dsta[e];
        atomicAdd(&h[(rel ? nbuk : 0) + (d >> shift)], 1);
    }
    __syncthreads();
    for (int i = threadIdx.x; i < 2 * nbuk; i += blockDim.x)
        if (h[i]) atomicAdd(&bcnt2[i], h[i]);
}

__global__ void bscan_kernel(const int* __restrict__ bcnt, int* __restrict__ bbase,
                             int* __restrict__ bcursor, int nbuk2,
                             int* __restrict__ rowptr2, int n2, int Et) {
    __shared__ int s[256];
    int t = threadIdx.x;
    int v = (t < nbuk2) ? bcnt[t] : 0;
    s[t] = v;
    __syncthreads();
    #pragma unroll
    for (int d = 1; d < 256; d <<= 1) {
        int u = (t >= d) ? s[t - d] : 0;
        __syncthreads();
        s[t] += u;
        __syncthreads();
    }
    if (t < nbuk2) { int e = s[t] - v; bbase[t] = e; bcursor[t] = e; }
    if (t == 0) rowptr2[n2] = Et;
}

// Bin (src, dst2) pairs by combined bucket id, chunk-local LDS counting.
__global__ void bfill2_kernel(const int* __restrict__ eia, const int* __restrict__ eib,
                              int* __restrict__ bcursor, int2* __restrict__ pairs,
                              int Ea, int Eb, int Et, int shift, int nbuk, int n) {
    __shared__ int cnt[MAXBUK];
    __shared__ int base[MAXBUK];
    __shared__ int off[MAXBUK];
    const int t = threadIdx.x;
    const long long e0 = (long long)blockIdx.x * BF_CHUNK;
    const int nedge = (int)min((long long)BF_CHUNK, (long long)Et - e0);
    const int nbuk2 = 2 * nbuk;
    for (int i = t; i < nbuk2; i += 256) cnt[i] = 0;
    __syncthreads();
    for (int i = t; i < nedge; i += 256) {
        long long e = e0 + i;
        int rel = (e >= Ea);
        int d = rel ? eib[Eb + (e - Ea)] : eia[Ea + e];
        atomicAdd(&cnt[(rel ? nbuk : 0) + (d >> shift)], 1);
    }
    __syncthreads();
    for (int i = t; i < nbuk2; i += 256) {
        off[i] = 0;
        base[i] = cnt[i] ? atomicAdd(&bcursor[i], cnt[i]) : 0;
    }
    __syncthreads();
    for (int i = t; i < nedge; i += 256) {
        long long e = e0 + i;
        int rel = (e >= Ea);
        int s, d;
        if (rel) { s = eib[e - Ea]; d = eib[Eb + (e - Ea)]; }
        else     { s = eia[e];      d = eia[Ea + e]; }
        int b = (rel ? nbuk : 0) + (d >> shift);
        int p = base[b] + atomicAdd(&off[b], 1);
        pairs[p] = make_int2(s, (rel ? n : 0) + d);
    }
}

// Per-bucket CSR build: LDS-only node counting + scan + cursor placement.
template<int NPB>
__global__ void bucket_csr_kernel(const int2* __restrict__ pairs,
                                  const int* __restrict__ bbase2, const int* __restrict__ bcnt2,
                                  int* __restrict__ rowptr2, float* __restrict__ dinv2,
                                  int* __restrict__ col2,
                                  int nbuk, int shift, int n) {
    constexpr int BLK = 1024;
    constexpr int K = NPB / BLK;
    __shared__ int cnt[NPB];
    __shared__ int ssum[BLK];
    const int b = blockIdx.x;
    const int t = threadIdx.x;
    const int rel = (b >= nbuk);
    const int blocal = rel ? b - nbuk : b;
    const int nodelo = blocal << shift;
    const int node0 = (rel ? n : 0) + nodelo;
    const int NN = min(NPB, n - nodelo);
    const int p0 = bbase2[b];
    const int p1 = p0 + bcnt2[b];

    #pragma unroll
    for (int k = 0; k < K; ++k) cnt[t + k * BLK] = 0;
    __syncthreads();
    for (int idx = p0 + t; idx < p1; idx += BLK)
        atomicAdd(&cnt[pairs[idx].y - node0], 1);
    __syncthreads();

    int a[K]; int s = 0;
    #pragma unroll
    for (int k = 0; k < K; ++k) { a[k] = cnt[t * K + k]; s += a[k]; }
    ssum[t] = s;
    __syncthreads();
    #pragma unroll
    for (int d = 1; d < BLK; d <<= 1) {
        int u = (t >= d) ? ssum[t - d] : 0;
        __syncthreads();
        ssum[t] += u;
        __syncthreads();
    }
    int run = p0 + ssum[t] - s;
    __syncthreads();
    #pragma unroll
    for (int k = 0; k < K; ++k) {
        int j = t * K + k;
        cnt[j] = run;
        if (j < NN) {
            rowptr2[node0 + j] = run;
            dinv2[node0 + j] = rsqrtf((float)(a[k] + 1));
        }
        run += a[k];
    }
    __syncthreads();
    for (int idx = p0 + t; idx < p1; idx += BLK) {
        int2 p = pairs[idx];
        int pos = atomicAdd(&cnt[p.y - node0], 1);
        col2[pos] = p.x;
    }
}

// ---- MFMA dual-weight GEMM (layer 1): ya|yb = (Xbf16 @ [Wa|Wb]) * dinv, bf16 out ----
__global__ void gemm2_mfma_bf16_kernel(const float* __restrict__ X,
                                       const float* __restrict__ Wa, const float* __restrict__ Wb,
                                       const float* __restrict__ dinva, const float* __restrict__ dinvb,
                                       ushort_t* __restrict__ ya, ushort_t* __restrict__ yb, int n) {
    __shared__ ushort_t Xs[64 * XS_STRIDE];
    __shared__ ushort_t Wt[128 * XS_STRIDE];
    const int tid = threadIdx.x;
    const int rowbase = blockIdx.x * 64;

    {
        int row = tid >> 2, cg = tid & 3;
        int grow = rowbase + row;
        float4 v[4];
        if (grow < n) {
            const float4* xr = reinterpret_cast<const float4*>(X + (size_t)grow * 64 + cg * 16);
            v[0] = xr[0]; v[1] = xr[1]; v[2] = xr[2]; v[3] = xr[3];
        } else {
            v[0] = v[1] = v[2] = v[3] = make_float4(0.f, 0.f, 0.f, 0.f);
        }
        ushort_t* dst = &Xs[row * XS_STRIDE + cg * 16];
        #pragma unroll
        for (int q = 0; q < 4; ++q) {
            dst[q * 4 + 0] = f2bf(v[q].x); dst[q * 4 + 1] = f2bf(v[q].y);
            dst[q * 4 + 2] = f2bf(v[q].z); dst[q * 4 + 3] = f2bf(v[q].w);
        }
    }
    for (int idx = tid; idx < 4096; idx += 256) {
        int k = idx >> 6, c = idx & 63;
        Wt[c * XS_STRIDE + k] = f2bf(Wa[idx]);
        Wt[(64 + c) * XS_STRIDE + k] = f2bf(Wb[idx]);
    }
    __syncthreads();

    const int wid = tid >> 6, lane = tid & 63;
    const int lrow = lane & 15;
    const int lk = (lane >> 4) * 8;

    short8_t a0 = *reinterpret_cast<const short8_t*>(&Xs[(wid * 16 + lrow) * XS_STRIDE + lk]);
    short8_t a1 = *reinterpret_cast<const short8_t*>(&Xs[(wid * 16 + lrow) * XS_STRIDE + 32 + lk]);

    f32x4 acc[8];
    #pragma unroll
    for (int ct = 0; ct < 8; ++ct) {
        short8_t b0 = *reinterpret_cast<const short8_t*>(&Wt[(ct * 16 + lrow) * XS_STRIDE + lk]);
        short8_t b1 = *reinterpret_cast<const short8_t*>(&Wt[(ct * 16 + lrow) * XS_STRIDE + 32 + lk]);
        f32x4 c = {0.f, 0.f, 0.f, 0.f};
        c = __builtin_amdgcn_mfma_f32_16x16x32_bf16(a0, b0, c, 0, 0, 0);
        c = __builtin_amdgcn_mfma_f32_16x16x32_bf16(a1, b1, c, 0, 0, 0);
        acc[ct] = c;
    }

    const int rq = (lane >> 4) * 4;
    #pragma unroll
    for (int r = 0; r < 4; ++r) {
        int grow = rowbase + wid * 16 + rq + r;
        if (grow < n) {
            float sa = dinva[grow], sb = dinvb[grow];
            #pragma unroll
            for (int ct = 0; ct < 8; ++ct) {
                int col = ct * 16 + lrow;
                float v = acc[ct][r];
                if (col < 64) ya[(size_t)grow * 64 + col] = f2bf(v * sa);
                else          yb[(size_t)grow * 64 + (col - 64)] = f2bf(v * sb);
            }
        }
    }
}

// ---- fused: dual-relation aggregation (F=64) + ReLU + layer-2 projection (64->16+16) ----
// Each wave processes 16 consecutive nodes, buffers h rows (bf16) in LDS, then
// projects with 4 MFMAs against pre-staged W2t and writes z directly. No C buffer.
__global__ void agg64_proj_kernel(const ushort_t* __restrict__ ya, const ushort_t* __restrict__ yb,
                                  const int* __restrict__ rp2, const int* __restrict__ col2,
                                  const float* __restrict__ dinv2,
                                  const float* __restrict__ b1a, const float* __restrict__ b1b,
                                  const float* __restrict__ W2a, const float* __restrict__ W2b,
                                  ushort_t* __restrict__ za, ushort_t* __restrict__ zb, int n) {
    __shared__ ushort_t W2t[32 * XS_STRIDE];        // [combined col][k], bf16
    __shared__ ushort_t htile[4][16 * XS_STRIDE];   // per-wave h tile [node row][feature]
    const int tid = threadIdx.x;
    // stage W2 transposed (cols 0-15 = W2a, 16-31 = W2b)
    for (int idx = tid; idx < 2048; idx += 256) {
        int c = idx & 31, k = idx >> 5;
        float v = (c < 16) ? W2a[k * 16 + c] : W2b[k * 16 + (c - 16)];
        W2t[c * XS_STRIDE + k] = f2bf(v);
    }
    __syncthreads();

    const int lane = tid & 63;
    const int wid  = tid >> 6;
    const int gw   = (blockIdx.x * blockDim.x + tid) >> 6;
    const int nw   = (gridDim.x * blockDim.x) >> 6;
    const float bias = b1a[lane] + b1b[lane];
    ushort_t* ht = &htile[wid][0];
    const int lrow = lane & 15;
    const int lk = (lane >> 4) * 8;
    const int rq = (lane >> 4) * 4;
    const int ntiles = (n + 15) >> 4;

    for (int tile = gw; tile < ntiles; tile += nw) {
        const int ibase = tile << 4;
        for (int r16 = 0; r16 < 16; ++r16) {
            const int i = ibase + r16;
            float hv = 0.0f;
            if (i < n) {
                float acca = bf2f(ya[(size_t)i * 64 + lane]);
                {
                    const int e0 = rp2[i], e1 = rp2[i + 1];
                    for (int base = e0; base < e1; base += 64) {
                        const int m = min(64, e1 - base);
                        int c = (lane < m) ? col2[base + lane] : 0;
                        int j = 0;
                        for (; j + 4 <= m; j += 4) {
                            int s0 = __shfl(c, j), s1 = __shfl(c, j + 1);
                            int s2 = __shfl(c, j + 2), s3 = __shfl(c, j + 3);
                            acca += bf2f(ya[(size_t)s0 * 64 + lane]);
                            acca += bf2f(ya[(size_t)s1 * 64 + lane]);
                            acca += bf2f(ya[(size_t)s2 * 64 + lane]);
                            acca += bf2f(ya[(size_t)s3 * 64 + lane]);
                        }
                        for (; j < m; ++j)
                            acca += bf2f(ya[(size_t)__shfl(c, j) * 64 + lane]);
                    }
                }
                float accb = bf2f(yb[(size_t)i * 64 + lane]);
                {
                    const int e0 = rp2[n + i], e1 = rp2[n + i + 1];
                    for (int base = e0; base < e1; base += 64) {
                        const int m = min(64, e1 - base);
                        int c = (lane < m) ? col2[base + lane] : 0;
                        int j = 0;
                        for (; j + 4 <= m; j += 4) {
                            int s0 = __shfl(c, j), s1 = __shfl(c, j + 1);
                            int s2 = __shfl(c, j + 2), s3 = __shfl(c, j + 3);
                            accb += bf2f(yb[(size_t)s0 * 64 + lane]);
                            accb += bf2f(yb[(size_t)s1 * 64 + lane]);
                            accb += bf2f(yb[(size_t)s2 * 64 + lane]);
                            accb += bf2f(yb[(size_t)s3 * 64 + lane]);
                        }
                        for (; j < m; ++j)
                            accb += bf2f(yb[(size_t)__shfl(c, j) * 64 + lane]);
                    }
                }
                float v = 0.5f * (acca * dinv2[i] + accb * dinv2[n + i] + bias);
                hv = fmaxf(v, 0.0f);
            }
            ht[r16 * XS_STRIDE + lane] = f2bf(hv);
        }

        // project: A = htile (16 nodes x 64 feats), B = W2t (64 x 32)
        short8_t a0 = *reinterpret_cast<const short8_t*>(&ht[lrow * XS_STRIDE + lk]);
        short8_t a1 = *reinterpret_cast<const short8_t*>(&ht[lrow * XS_STRIDE + 32 + lk]);
        f32x4 c0 = {0.f, 0.f, 0.f, 0.f}, c1 = {0.f, 0.f, 0.f, 0.f};
        {
            short8_t b0 = *reinterpret_cast<const short8_t*>(&W2t[lrow * XS_STRIDE + lk]);
            short8_t b1 = *reinterpret_cast<const short8_t*>(&W2t[lrow * XS_STRIDE + 32 + lk]);
            c0 = __builtin_amdgcn_mfma_f32_16x16x32_bf16(a0, b0, c0, 0, 0, 0);
            c0 = __builtin_amdgcn_mfma_f32_16x16x32_bf16(a1, b1, c0, 0, 0, 0);
        }
        {
            short8_t b0 = *reinterpret_cast<const short8_t*>(&W2t[(16 + lrow) * XS_STRIDE + lk]);
            short8_t b1 = *reinterpret_cast<const short8_t*>(&W2t[(16 + lrow) * XS_STRIDE + 32 + lk]);
            c1 = __builtin_amdgcn_mfma_f32_16x16x32_bf16(a0, b0, c1, 0, 0, 0);
            c1 = __builtin_amdgcn_mfma_f32_16x16x32_bf16(a1, b1, c1, 0, 0, 0);
        }
        #pragma unroll
        for (int r = 0; r < 4; ++r) {
            const int node = ibase + rq + r;
            if (node < n) {
                za[(size_t)node * 16 + lrow] = f2bf(c0[r] * dinv2[node]);
                zb[(size_t)node * 16 + lrow] = f2bf(c1[r] * dinv2[n + node]);
            }
        }
    }
}

// ---- fused dual-relation aggregation, layer 2 (bf16 gathers, F=16) ----
__global__ void agg16_dual_kernel(const ushort_t* __restrict__ za, const ushort_t* __restrict__ zb,
                                  const int* __restrict__ rp2, const int* __restrict__ col2,
                                  const float* __restrict__ dinv2,
                                  const float* __restrict__ ba, const float* __restrict__ bb,
                                  float* __restrict__ outp, int n) {
    const int lane = threadIdx.x & 63;
    const int f    = lane & 15;
    const int sub  = lane >> 4;
    const int wid  = (blockIdx.x * blockDim.x + threadIdx.x) >> 6;
    const int nw   = (gridDim.x * blockDim.x) >> 6;
    const float bias = ba[f] + bb[f];
    for (int i = wid; i < n; i += nw) {
        float acca = (sub == 0) ? bf2f(za[(size_t)i * 16 + f]) : 0.0f;
        {
            const int e0 = rp2[i], e1 = rp2[i + 1];
            for (int e = e0 + sub; e < e1; e += 4)
                acca += bf2f(za[(size_t)col2[e] * 16 + f]);
        }
        float accb = (sub == 0) ? bf2f(zb[(size_t)i * 16 + f]) : 0.0f;
        {
            const int e0 = rp2[n + i], e1 = rp2[n + i + 1];
            for (int e = e0 + sub; e < e1; e += 4)
                accb += bf2f(zb[(size_t)col2[e] * 16 + f]);
        }
        float v = acca * dinv2[i] + accb * dinv2[n + i];
        v += __shfl_xor(v, 16);
        v += __shfl_xor(v, 32);
        if (sub == 0) outp[(size_t)i * 16 + f] = 0.5f * (v + bias);
    }
}

extern "C" void kernel_launch(void* const* d_in, const int* in_sizes, int n_in,
                              void* d_out, int out_size, void* d_ws, size_t ws_size,
                              hipStream_t stream) {
    const float* x   = (const float*)d_in[0];
    const int*   eia = (const int*)d_in[1];
    const int*   eib = (const int*)d_in[2];
    const float* W1a = (const float*)d_in[3];
    const float* b1a = (const float*)d_in[4];
    const float* W1b = (const float*)d_in[5];
    const float* b1b = (const float*)d_in[6];
    const float* W2a = (const float*)d_in[7];
    const float* b2a = (const float*)d_in[8];
    const float* W2b = (const float*)d_in[9];
    const float* b2b = (const float*)d_in[10];
    float* out = (float*)d_out;

    const int n  = in_sizes[0] / 64;
    const int Ea = in_sizes[1] / 2;
    const int Eb = in_sizes[2] / 2;
    const int Et = Ea + Eb;
    const int n2 = 2 * n;

    int shift = 10;
    while ((((long long)n + (1LL << shift) - 1) >> shift) > 128) ++shift;
    const int nbuk = (int)(((long long)n + (1LL << shift) - 1) >> shift);
    const int nbuk2 = 2 * nbuk;

    char* wsp = (char*)d_ws;
    size_t off = 0;
    auto carve = [&](size_t elems) { void* p = wsp + off; off += ((elems + 3) & ~(size_t)3) * 4; return p; };
    float* dinv2    = (float*)carve(n2);
    int*   rowptr2  = (int*)carve(n2 + 1);
    int*   bcnt2    = (int*)carve(MAXBUK);
    int*   bbase2   = (int*)carve(MAXBUK);
    int*   bcursor2 = (int*)carve(MAXBUK);
    int*   col2     = (int*)carve(Et);
    ushort_t* ya    = (ushort_t*)carve((size_t)32 * n);   // 64n bf16
    ushort_t* yb    = (ushort_t*)carve((size_t)32 * n);
    // big union: pairs (2*Et words) dead after bucket_csr; then za/zb (16n words total)
    size_t big_words = (size_t)2 * Et > (size_t)16 * n ? (size_t)2 * Et : (size_t)16 * n;
    void*  big      = carve(big_words);
    int2*  pairs    = (int2*)big;
    ushort_t* za    = (ushort_t*)big;                     // 16n bf16
    ushort_t* zb    = za + (size_t)16 * n;

    const int T = 256;
    auto cdiv = [](long long a, long long b) { return (unsigned)((a + b - 1) / b); };

    // ---- combined CSR build ----
    zero_int_kernel<<<1, 256, 0, stream>>>(bcnt2, MAXBUK);
    bhist2_kernel<<<cdiv(Et, (long long)T * 16), T, 0, stream>>>(eia + Ea, eib + Eb, bcnt2,
                                                                 Ea, Et, shift, nbuk);
    bscan_kernel<<<1, 256, 0, stream>>>(bcnt2, bbase2, bcursor2, nbuk2, rowptr2, n2, Et);
    bfill2_kernel<<<cdiv(Et, BF_CHUNK), T, 0, stream>>>(eia, eib, bcursor2, pairs,
                                                        Ea, Eb, Et, shift, nbuk, n);
    if (shift == 10)
        bucket_csr_kernel<1024><<<nbuk2, 1024, 0, stream>>>(pairs, bbase2, bcnt2, rowptr2, dinv2,
                                                            col2, nbuk, shift, n);
    else if (shift == 11)
        bucket_csr_kernel<2048><<<nbuk2, 1024, 0, stream>>>(pairs, bbase2, bcnt2, rowptr2, dinv2,
                                                            col2, nbuk, shift, n);
    else
        bucket_csr_kernel<4096><<<nbuk2, 1024, 0, stream>>>(pairs, bbase2, bcnt2, rowptr2, dinv2,
                                                            col2, nbuk, shift, n);

    const unsigned AGG_GRID = 2048;

    // ---- layer 1 GEMM ----
    gemm2_mfma_bf16_kernel<<<cdiv(n, 64), T, 0, stream>>>(x, W1a, W1b, dinv2, dinv2 + n, ya, yb, n);
    // ---- fused agg + relu + layer-2 projection ----
    agg64_proj_kernel<<<AGG_GRID, T, 0, stream>>>(ya, yb, rowptr2, col2, dinv2,
                                                  b1a, b1b, W2a, W2b, za, zb, n);
    // ---- layer-2 aggregation ----
    agg16_dual_kernel<<<AGG_GRID, T, 0, stream>>>(za, zb, rowptr2, col2, dinv2, b2a, b2b, out, n);
}

// Round 9
// 238.475 us; speedup vs baseline: 1.8524x; 1.0797x over previous
//
#include <hip/hip_runtime.h>

#define LDS_XPAD 68
#define XS_STRIDE 72
#define MAXBUK 256
#define BF_CHUNK 4096

typedef unsigned short ushort_t;
typedef unsigned int uint_t;
typedef __attribute__((ext_vector_type(8))) short short8_t;
typedef __attribute__((ext_vector_type(4))) float f32x4;

__device__ __forceinline__ ushort_t f2bf(float x) {
    uint_t u = __float_as_uint(x);
    uint_t r = (u + 0x7FFFu + ((u >> 16) & 1u)) >> 16;
    return (ushort_t)r;
}
__device__ __forceinline__ float bf2f(ushort_t h) {
    return __uint_as_float((uint_t)h << 16);
}

__global__ void zero_int_kernel(int* p, int n) {
    int i = blockIdx.x * blockDim.x + threadIdx.x;
    if (i < n) p[i] = 0;
}

__global__ void bhist2_kernel(const int* __restrict__ dsta, const int* __restrict__ dstb,
                              int* __restrict__ bcnt2,
                              int Ea, int Et, int shift, int nbuk) {
    __shared__ int h[MAXBUK];
    for (int i = threadIdx.x; i < 2 * nbuk; i += blockDim.x) h[i] = 0;
    __syncthreads();
    int stride = gridDim.x * blockDim.x;
    for (int e = blockIdx.x * blockDim.x + threadIdx.x; e < Et; e += stride) {
        int rel = (e >= Ea);
        int d = rel ? dstb[e - Ea] : dsta[e];
        atomicAdd(&h[(rel ? nbuk : 0) + (d >> shift)], 1);
    }
    __syncthreads();
    for (int i = threadIdx.x; i < 2 * nbuk; i += blockDim.x)
        if (h[i]) atomicAdd(&bcnt2[i], h[i]);
}

__global__ void bscan_kernel(const int* __restrict__ bcnt, int* __restrict__ bbase,
                             int* __restrict__ bcursor, int nbuk2,
                             int* __restrict__ rowptr2, int n2, int Et) {
    __shared__ int s[256];
    int t = threadIdx.x;
    int v = (t < nbuk2) ? bcnt[t] : 0;
    s[t] = v;
    __syncthreads();
    #pragma unroll
    for (int d = 1; d < 256; d <<= 1) {
        int u = (t >= d) ? s[t - d] : 0;
        __syncthreads();
        s[t] += u;
        __syncthreads();
    }
    if (t < nbuk2) { int e = s[t] - v; bbase[t] = e; bcursor[t] = e; }
    if (t == 0) rowptr2[n2] = Et;
}

__global__ void bfill2_kernel(const int* __restrict__ eia, const int* __restrict__ eib,
                              int* __restrict__ bcursor, int2* __restrict__ pairs,
                              int Ea, int Eb, int Et, int shift, int nbuk, int n) {
    __shared__ int cnt[MAXBUK];
    __shared__ int base[MAXBUK];
    __shared__ int off[MAXBUK];
    const int t = threadIdx.x;
    const long long e0 = (long long)blockIdx.x * BF_CHUNK;
    const int nedge = (int)min((long long)BF_CHUNK, (long long)Et - e0);
    const int nbuk2 = 2 * nbuk;
    for (int i = t; i < nbuk2; i += 256) cnt[i] = 0;
    __syncthreads();
    for (int i = t; i < nedge; i += 256) {
        long long e = e0 + i;
        int rel = (e >= Ea);
        int d = rel ? eib[Eb + (e - Ea)] : eia[Ea + e];
        atomicAdd(&cnt[(rel ? nbuk : 0) + (d >> shift)], 1);
    }
    __syncthreads();
    for (int i = t; i < nbuk2; i += 256) {
        off[i] = 0;
        base[i] = cnt[i] ? atomicAdd(&bcursor[i], cnt[i]) : 0;
    }
    __syncthreads();
    for (int i = t; i < nedge; i += 256) {
        long long e = e0 + i;
        int rel = (e >= Ea);
        int s, d;
        if (rel) { s = eib[e - Ea]; d = eib[Eb + (e - Ea)]; }
        else     { s = eia[e];      d = eia[Ea + e]; }
        int b = (rel ? nbuk : 0) + (d >> shift);
        int p = base[b] + atomicAdd(&off[b], 1);
        pairs[p] = make_int2(s, (rel ? n : 0) + d);
    }
}

template<int NPB>
__global__ void bucket_csr_kernel(const int2* __restrict__ pairs,
                                  const int* __restrict__ bbase2, const int* __restrict__ bcnt2,
                                  int* __restrict__ rowptr2, float* __restrict__ dinv2,
                                  int* __restrict__ col2,
                                  int nbuk, int shift, int n) {
    constexpr int BLK = 1024;
    constexpr int K = NPB / BLK;
    __shared__ int cnt[NPB];
    __shared__ int ssum[BLK];
    const int b = blockIdx.x;
    const int t = threadIdx.x;
    const int rel = (b >= nbuk);
    const int blocal = rel ? b - nbuk : b;
    const int nodelo = blocal << shift;
    const int node0 = (rel ? n : 0) + nodelo;
    const int NN = min(NPB, n - nodelo);
    const int p0 = bbase2[b];
    const int p1 = p0 + bcnt2[b];

    #pragma unroll
    for (int k = 0; k < K; ++k) cnt[t + k * BLK] = 0;
    __syncthreads();
    for (int idx = p0 + t; idx < p1; idx += BLK)
        atomicAdd(&cnt[pairs[idx].y - node0], 1);
    __syncthreads();

    int a[K]; int s = 0;
    #pragma unroll
    for (int k = 0; k < K; ++k) { a[k] = cnt[t * K + k]; s += a[k]; }
    ssum[t] = s;
    __syncthreads();
    #pragma unroll
    for (int d = 1; d < BLK; d <<= 1) {
        int u = (t >= d) ? ssum[t - d] : 0;
        __syncthreads();
        ssum[t] += u;
        __syncthreads();
    }
    int run = p0 + ssum[t] - s;
    __syncthreads();
    #pragma unroll
    for (int k = 0; k < K; ++k) {
        int j = t * K + k;
        cnt[j] = run;
        if (j < NN) {
            rowptr2[node0 + j] = run;
            dinv2[node0 + j] = rsqrtf((float)(a[k] + 1));
        }
        run += a[k];
    }
    __syncthreads();
    for (int idx = p0 + t; idx < p1; idx += BLK) {
        int2 p = pairs[idx];
        int pos = atomicAdd(&cnt[p.y - node0], 1);
        col2[pos] = p.x;
    }
}

// ---- MFMA dual-weight GEMM (layer 1): ya|yb = (Xbf16 @ [Wa|Wb]) * dinv, bf16 out ----
__global__ void gemm2_mfma_bf16_kernel(const float* __restrict__ X,
                                       const float* __restrict__ Wa, const float* __restrict__ Wb,
                                       const float* __restrict__ dinva, const float* __restrict__ dinvb,
                                       ushort_t* __restrict__ ya, ushort_t* __restrict__ yb, int n) {
    __shared__ ushort_t Xs[64 * XS_STRIDE];
    __shared__ ushort_t Wt[128 * XS_STRIDE];
    const int tid = threadIdx.x;
    const int rowbase = blockIdx.x * 64;

    {
        int row = tid >> 2, cg = tid & 3;
        int grow = rowbase + row;
        float4 v[4];
        if (grow < n) {
            const float4* xr = reinterpret_cast<const float4*>(X + (size_t)grow * 64 + cg * 16);
            v[0] = xr[0]; v[1] = xr[1]; v[2] = xr[2]; v[3] = xr[3];
        } else {
            v[0] = v[1] = v[2] = v[3] = make_float4(0.f, 0.f, 0.f, 0.f);
        }
        ushort_t* dst = &Xs[row * XS_STRIDE + cg * 16];
        #pragma unroll
        for (int q = 0; q < 4; ++q) {
            dst[q * 4 + 0] = f2bf(v[q].x); dst[q * 4 + 1] = f2bf(v[q].y);
            dst[q * 4 + 2] = f2bf(v[q].z); dst[q * 4 + 3] = f2bf(v[q].w);
        }
    }
    for (int idx = tid; idx < 4096; idx += 256) {
        int k = idx >> 6, c = idx & 63;
        Wt[c * XS_STRIDE + k] = f2bf(Wa[idx]);
        Wt[(64 + c) * XS_STRIDE + k] = f2bf(Wb[idx]);
    }
    __syncthreads();

    const int wid = tid >> 6, lane = tid & 63;
    const int lrow = lane & 15;
    const int lk = (lane >> 4) * 8;

    short8_t a0 = *reinterpret_cast<const short8_t*>(&Xs[(wid * 16 + lrow) * XS_STRIDE + lk]);
    short8_t a1 = *reinterpret_cast<const short8_t*>(&Xs[(wid * 16 + lrow) * XS_STRIDE + 32 + lk]);

    f32x4 acc[8];
    #pragma unroll
    for (int ct = 0; ct < 8; ++ct) {
        short8_t b0 = *reinterpret_cast<const short8_t*>(&Wt[(ct * 16 + lrow) * XS_STRIDE + lk]);
        short8_t b1 = *reinterpret_cast<const short8_t*>(&Wt[(ct * 16 + lrow) * XS_STRIDE + 32 + lk]);
        f32x4 c = {0.f, 0.f, 0.f, 0.f};
        c = __builtin_amdgcn_mfma_f32_16x16x32_bf16(a0, b0, c, 0, 0, 0);
        c = __builtin_amdgcn_mfma_f32_16x16x32_bf16(a1, b1, c, 0, 0, 0);
        acc[ct] = c;
    }

    const int rq = (lane >> 4) * 4;
    #pragma unroll
    for (int r = 0; r < 4; ++r) {
        int grow = rowbase + wid * 16 + rq + r;
        if (grow < n) {
            float sa = dinva[grow], sb = dinvb[grow];
            #pragma unroll
            for (int ct = 0; ct < 8; ++ct) {
                int col = ct * 16 + lrow;
                float v = acc[ct][r];
                if (col < 64) ya[(size_t)grow * 64 + col] = f2bf(v * sa);
                else          yb[(size_t)grow * 64 + (col - 64)] = f2bf(v * sb);
            }
        }
    }
}

// ---- dual-weight GEMM (layer 2, M=16): reads h (f32), writes bf16 z ----
__global__ void gemm2_scale_f32_kernel(const float* __restrict__ X,
                                       const float* __restrict__ Wa, const float* __restrict__ Wb,
                                       const float* __restrict__ dinva, const float* __restrict__ dinvb,
                                       ushort_t* __restrict__ ya, ushort_t* __restrict__ yb, int n) {
    constexpr int M = 16;
    __shared__ float xs[64 * LDS_XPAD];
    __shared__ float wsa[64 * M];
    __shared__ float wsb[64 * M];
    const int tid = threadIdx.x;
    const int row = tid >> 2;
    const int cg  = tid & 3;
    const int grow = blockIdx.x * 64 + row;

    {
        float4 v0, v1, v2, v3;
        if (grow < n) {
            const float4* xr = reinterpret_cast<const float4*>(X + (size_t)grow * 64 + cg * 16);
            v0 = xr[0]; v1 = xr[1]; v2 = xr[2]; v3 = xr[3];
        } else {
            v0 = v1 = v2 = v3 = make_float4(0.f, 0.f, 0.f, 0.f);
        }
        float4* xd = reinterpret_cast<float4*>(&xs[row * LDS_XPAD + cg * 16]);
        xd[0] = v0; xd[1] = v1; xd[2] = v2; xd[3] = v3;
    }
    {
        const float4* sa = reinterpret_cast<const float4*>(Wa);
        const float4* sb = reinterpret_cast<const float4*>(Wb);
        float4* da = reinterpret_cast<float4*>(wsa);
        float4* db = reinterpret_cast<float4*>(wsb);
        if (tid < 64 * M / 4) { da[tid] = sa[tid]; db[tid] = sb[tid]; }
    }
    __syncthreads();

    constexpr int CPT = 4;
    float acca[CPT], accb[CPT];
    #pragma unroll
    for (int j = 0; j < CPT; ++j) { acca[j] = 0.0f; accb[j] = 0.0f; }

    for (int k = 0; k < 64; ++k) {
        float xk = xs[row * LDS_XPAD + k];
        #pragma unroll
        for (int j = 0; j < CPT; ++j) {
            acca[j] += xk * wsa[k * M + cg * CPT + j];
            accb[j] += xk * wsb[k * M + cg * CPT + j];
        }
    }

    if (grow < n) {
        float sa = dinva[grow], sb = dinvb[grow];
        uint2 pa, pb;
        pa.x = (uint_t)f2bf(acca[0] * sa) | ((uint_t)f2bf(acca[1] * sa) << 16);
        pa.y = (uint_t)f2bf(acca[2] * sa) | ((uint_t)f2bf(acca[3] * sa) << 16);
        pb.x = (uint_t)f2bf(accb[0] * sb) | ((uint_t)f2bf(accb[1] * sb) << 16);
        pb.y = (uint_t)f2bf(accb[2] * sb) | ((uint_t)f2bf(accb[3] * sb) << 16);
        *reinterpret_cast<uint2*>(ya + (size_t)grow * M + cg * CPT) = pa;
        *reinterpret_cast<uint2*>(yb + (size_t)grow * M + cg * CPT) = pb;
    }
}

// ---- fused dual-relation aggregation, layer 1 (bf16, F=64) ----
// a-stream and b-stream INTERLEAVED: 8 gathers in flight per wave.
__global__ void agg64_dual_kernel(const ushort_t* __restrict__ ya, const ushort_t* __restrict__ yb,
                                  const int* __restrict__ rp2, const int* __restrict__ col2,
                                  const float* __restrict__ dinv2,
                                  const float* __restrict__ ba, const float* __restrict__ bb,
                                  float* __restrict__ h, int n) {
    const int lane = threadIdx.x & 63;
    const int gw   = (blockIdx.x * blockDim.x + threadIdx.x) >> 6;
    const int nw   = (gridDim.x * blockDim.x) >> 6;
    const float bias = ba[lane] + bb[lane];
    for (int i = gw; i < n; i += nw) {
        const int e0a = rp2[i],     e1a = rp2[i + 1];
        const int e0b = rp2[n + i], e1b = rp2[n + i + 1];
        float acca = bf2f(ya[(size_t)i * 64 + lane]);
        float accb = bf2f(yb[(size_t)i * 64 + lane]);
        const int ma = min(64, e1a - e0a);
        const int mb = min(64, e1b - e0b);
        int cva = (lane < ma) ? col2[e0a + lane] : 0;
        int cvb = (lane < mb) ? col2[e0b + lane] : 0;
        const int mn = min(ma, mb);
        int j = 0;
        for (; j + 4 <= mn; j += 4) {
            int a0 = __shfl(cva, j),     b0 = __shfl(cvb, j);
            int a1 = __shfl(cva, j + 1), b1 = __shfl(cvb, j + 1);
            int a2 = __shfl(cva, j + 2), b2 = __shfl(cvb, j + 2);
            int a3 = __shfl(cva, j + 3), b3 = __shfl(cvb, j + 3);
            float ga0 = bf2f(ya[(size_t)a0 * 64 + lane]);
            float gb0 = bf2f(yb[(size_t)b0 * 64 + lane]);
            float ga1 = bf2f(ya[(size_t)a1 * 64 + lane]);
            float gb1 = bf2f(yb[(size_t)b1 * 64 + lane]);
            float ga2 = bf2f(ya[(size_t)a2 * 64 + lane]);
            float gb2 = bf2f(yb[(size_t)b2 * 64 + lane]);
            float ga3 = bf2f(ya[(size_t)a3 * 64 + lane]);
            float gb3 = bf2f(yb[(size_t)b3 * 64 + lane]);
            acca += (ga0 + ga1) + (ga2 + ga3);
            accb += (gb0 + gb1) + (gb2 + gb3);
        }
        for (; j < mn; ++j) {
            float ga = bf2f(ya[(size_t)__shfl(cva, j) * 64 + lane]);
            float gb = bf2f(yb[(size_t)__shfl(cvb, j) * 64 + lane]);
            acca += ga; accb += gb;
        }
        for (int ja = j; ja < ma; ++ja)
            acca += bf2f(ya[(size_t)__shfl(cva, ja) * 64 + lane]);
        for (int jb = j; jb < mb; ++jb)
            accb += bf2f(yb[(size_t)__shfl(cvb, jb) * 64 + lane]);
        // rare: degree > 64
        for (int base = e0a + 64; base < e1a; base += 64) {
            const int m = min(64, e1a - base);
            int c = (lane < m) ? col2[base + lane] : 0;
            for (int jj = 0; jj < m; ++jj)
                acca += bf2f(ya[(size_t)__shfl(c, jj) * 64 + lane]);
        }
        for (int base = e0b + 64; base < e1b; base += 64) {
            const int m = min(64, e1b - base);
            int c = (lane < m) ? col2[base + lane] : 0;
            for (int jj = 0; jj < m; ++jj)
                accb += bf2f(yb[(size_t)__shfl(c, jj) * 64 + lane]);
        }
        float v = 0.5f * (acca * dinv2[i] + accb * dinv2[n + i] + bias);
        h[(size_t)i * 64 + lane] = fmaxf(v, 0.0f);
    }
}

// ---- fused dual-relation aggregation, layer 2 (bf16, F=16) ----
// 4 edge-slots per wave per stream; a/b streams interleaved 2-deep: 8 lines in flight.
__global__ void agg16_dual_kernel(const ushort_t* __restrict__ za, const ushort_t* __restrict__ zb,
                                  const int* __restrict__ rp2, const int* __restrict__ col2,
                                  const float* __restrict__ dinv2,
                                  const float* __restrict__ ba, const float* __restrict__ bb,
                                  float* __restrict__ outp, int n) {
    const int lane = threadIdx.x & 63;
    const int f    = lane & 15;
    const int sub  = lane >> 4;
    const int gw   = (blockIdx.x * blockDim.x + threadIdx.x) >> 6;
    const int nw   = (gridDim.x * blockDim.x) >> 6;
    const float bias = ba[f] + bb[f];
    for (int i = gw; i < n; i += nw) {
        const int e1a = rp2[i + 1],     e1b = rp2[n + i + 1];
        int ea = rp2[i] + sub,          eb = rp2[n + i] + sub;
        float acca = (sub == 0) ? bf2f(za[(size_t)i * 16 + f]) : 0.0f;
        float accb = (sub == 0) ? bf2f(zb[(size_t)i * 16 + f]) : 0.0f;
        for (; ea + 4 < e1a && eb + 4 < e1b; ea += 8, eb += 8) {
            int c0 = col2[ea], c1 = col2[ea + 4];
            int d0 = col2[eb], d1 = col2[eb + 4];
            float g0 = bf2f(za[(size_t)c0 * 16 + f]);
            float g1 = bf2f(za[(size_t)c1 * 16 + f]);
            float g2 = bf2f(zb[(size_t)d0 * 16 + f]);
            float g3 = bf2f(zb[(size_t)d1 * 16 + f]);
            acca += g0 + g1;
            accb += g2 + g3;
        }
        for (; ea < e1a; ea += 4) acca += bf2f(za[(size_t)col2[ea] * 16 + f]);
        for (; eb < e1b; eb += 4) accb += bf2f(zb[(size_t)col2[eb] * 16 + f]);
        float v = acca * dinv2[i] + accb * dinv2[n + i];
        v += __shfl_xor(v, 16);
        v += __shfl_xor(v, 32);
        if (sub == 0) outp[(size_t)i * 16 + f] = 0.5f * (v + bias);
    }
}

extern "C" void kernel_launch(void* const* d_in, const int* in_sizes, int n_in,
                              void* d_out, int out_size, void* d_ws, size_t ws_size,
                              hipStream_t stream) {
    const float* x   = (const float*)d_in[0];
    const int*   eia = (const int*)d_in[1];
    const int*   eib = (const int*)d_in[2];
    const float* W1a = (const float*)d_in[3];
    const float* b1a = (const float*)d_in[4];
    const float* W1b = (const float*)d_in[5];
    const float* b1b = (const float*)d_in[6];
    const float* W2a = (const float*)d_in[7];
    const float* b2a = (const float*)d_in[8];
    const float* W2b = (const float*)d_in[9];
    const float* b2b = (const float*)d_in[10];
    float* out = (float*)d_out;

    const int n  = in_sizes[0] / 64;
    const int Ea = in_sizes[1] / 2;
    const int Eb = in_sizes[2] / 2;
    const int Et = Ea + Eb;
    const int n2 = 2 * n;

    int shift = 10;
    while ((((long long)n + (1LL << shift) - 1) >> shift) > 128) ++shift;
    const int nbuk = (int)(((long long)n + (1LL << shift) - 1) >> shift);
    const int nbuk2 = 2 * nbuk;

    char* wsp = (char*)d_ws;
    size_t off = 0;
    auto carve = [&](size_t elems) { void* p = wsp + off; off += ((elems + 3) & ~(size_t)3) * 4; return p; };
    float* dinv2    = (float*)carve(n2);
    int*   rowptr2  = (int*)carve(n2 + 1);
    int*   bcnt2    = (int*)carve(MAXBUK);
    int*   bbase2   = (int*)carve(MAXBUK);
    int*   bcursor2 = (int*)carve(MAXBUK);
    int*   col2     = (int*)carve(Et);
    ushort_t* ya    = (ushort_t*)carve((size_t)32 * n);   // 64n bf16
    ushort_t* yb    = (ushort_t*)carve((size_t)32 * n);
    ushort_t* za    = (ushort_t*)carve((size_t)8 * n);    // 16n bf16
    ushort_t* zb    = (ushort_t*)carve((size_t)8 * n);
    // big union: pairs (2*Et words) dead after bucket_csr; then C = h (64n f32)
    size_t big_words = (size_t)2 * Et > (size_t)64 * n ? (size_t)2 * Et : (size_t)64 * n;
    void*  big      = carve(big_words);
    int2*  pairs    = (int2*)big;
    float* C        = (float*)big;

    const int T = 256;
    auto cdiv = [](long long a, long long b) { return (unsigned)((a + b - 1) / b); };

    // ---- combined CSR build ----
    zero_int_kernel<<<1, 256, 0, stream>>>(bcnt2, MAXBUK);
    bhist2_kernel<<<cdiv(Et, (long long)T * 16), T, 0, stream>>>(eia + Ea, eib + Eb, bcnt2,
                                                                 Ea, Et, shift, nbuk);
    bscan_kernel<<<1, 256, 0, stream>>>(bcnt2, bbase2, bcursor2, nbuk2, rowptr2, n2, Et);
    bfill2_kernel<<<cdiv(Et, BF_CHUNK), T, 0, stream>>>(eia, eib, bcursor2, pairs,
                                                        Ea, Eb, Et, shift, nbuk, n);
    if (shift == 10)
        bucket_csr_kernel<1024><<<nbuk2, 1024, 0, stream>>>(pairs, bbase2, bcnt2, rowptr2, dinv2,
                                                            col2, nbuk, shift, n);
    else if (shift == 11)
        bucket_csr_kernel<2048><<<nbuk2, 1024, 0, stream>>>(pairs, bbase2, bcnt2, rowptr2, dinv2,
                                                            col2, nbuk, shift, n);
    else
        bucket_csr_kernel<4096><<<nbuk2, 1024, 0, stream>>>(pairs, bbase2, bcnt2, rowptr2, dinv2,
                                                            col2, nbuk, shift, n);

    const unsigned AGG_GRID = 2048;

    // ---- layer 1 ----
    gemm2_mfma_bf16_kernel<<<cdiv(n, 64), T, 0, stream>>>(x, W1a, W1b, dinv2, dinv2 + n, ya, yb, n);
    agg64_dual_kernel<<<AGG_GRID, T, 0, stream>>>(ya, yb, rowptr2, col2, dinv2, b1a, b1b, C, n);

    // ---- layer 2 ----
    gemm2_scale_f32_kernel<<<cdiv(n, 64), T, 0, stream>>>(C, W2a, W2b, dinv2, dinv2 + n, za, zb, n);
    agg16_dual_kernel<<<AGG_GRID, T, 0, stream>>>(za, zb, rowptr2, col2, dinv2, b2a, b2b, out, n);
}